// Round 1
// baseline (3284.522 us; speedup 1.0000x reference)
//
#include <hip/hip_runtime.h>
#include <hip/hip_bf16.h>
#include <math.h>

#define NND 20000
#define NED 320000
#define DD  256
#define DEE 128

// ---------------------------------------------------------------------------
// Generic tiled fp32 GEMM: C[M, NO] = (ACCUM ? C : 0) + A[M,K] @ W^T (+ bias)
// A row-major with leading dim lda; W row-major [NO, ldw] (first K cols used).
// Tile 64x64, BK=16, 256 threads, 4x4 per thread.
// ---------------------------------------------------------------------------
template<bool ACCUM, bool BIAS>
__global__ __launch_bounds__(256)
void gemm_atw(const float* __restrict__ A, int lda,
              const float* __restrict__ W, int ldw,
              const float* __restrict__ bias,
              float* __restrict__ C, int ldc,
              int M, int K) {
    __shared__ float As[16][68];
    __shared__ float Ws[16][68];
    const int m0 = blockIdx.x * 64;
    const int n0 = blockIdx.y * 64;
    const int tid = threadIdx.x;
    const int ty = tid >> 4, tx = tid & 15;
    const int lr = tid >> 2, lk = (tid & 3) * 4;

    float acc[4][4] = {};
    for (int k0 = 0; k0 < K; k0 += 16) {
        int ar = m0 + lr; if (ar >= M) ar = M - 1;
        const float4 av = *(const float4*)(A + (size_t)ar * lda + k0 + lk);
        const float4 wv = *(const float4*)(W + (size_t)(n0 + lr) * ldw + k0 + lk);
        __syncthreads();
        As[lk+0][lr] = av.x; As[lk+1][lr] = av.y; As[lk+2][lr] = av.z; As[lk+3][lr] = av.w;
        Ws[lk+0][lr] = wv.x; Ws[lk+1][lr] = wv.y; Ws[lk+2][lr] = wv.z; Ws[lk+3][lr] = wv.w;
        __syncthreads();
        #pragma unroll
        for (int kk = 0; kk < 16; ++kk) {
            const float4 a4 = *(const float4*)&As[kk][ty*4];
            const float4 b4 = *(const float4*)&Ws[kk][tx*4];
            const float am[4] = {a4.x, a4.y, a4.z, a4.w};
            const float bm[4] = {b4.x, b4.y, b4.z, b4.w};
            #pragma unroll
            for (int i2 = 0; i2 < 4; ++i2)
                #pragma unroll
                for (int j2 = 0; j2 < 4; ++j2)
                    acc[i2][j2] = fmaf(am[i2], bm[j2], acc[i2][j2]);
        }
    }
    float4 bv = {0.f, 0.f, 0.f, 0.f};
    if (BIAS) bv = *(const float4*)(bias + n0 + tx*4);
    #pragma unroll
    for (int i2 = 0; i2 < 4; ++i2) {
        const int row = m0 + ty*4 + i2;
        if (row >= M) continue;
        float* cp = C + (size_t)row * ldc + n0 + tx*4;
        float4 o = {0.f, 0.f, 0.f, 0.f};
        if (ACCUM) o = *(const float4*)cp;
        float4 r;
        r.x = acc[i2][0] + bv.x + o.x;
        r.y = acc[i2][1] + bv.y + o.y;
        r.z = acc[i2][2] + bv.z + o.z;
        r.w = acc[i2][3] + bv.w + o.w;
        *(float4*)cp = r;
    }
}

// ---------------------------------------------------------------------------
// Edge kernel: per 64-edge x 64-out tile:
//   acc = edge_attr[64,128] @ We^T   (We rows [256, ldw=640], K=128)
//   val = ReLU(acc + U[dst] + V[src] + b1);  atomicAdd into s[dst]
// NED % 64 == 0 so no row guard.
// ---------------------------------------------------------------------------
__global__ __launch_bounds__(256)
void edge_msg(const float* __restrict__ EA,
              const float* __restrict__ W, int ldw,
              const float* __restrict__ b1,
              const float* __restrict__ U, const float* __restrict__ V,
              const int* __restrict__ src, const int* __restrict__ dst,
              float* __restrict__ sbuf) {
    __shared__ float As[16][68];
    __shared__ float Ws[16][68];
    const int e0 = blockIdx.x * 64;
    const int n0 = blockIdx.y * 64;
    const int tid = threadIdx.x;
    const int ty = tid >> 4, tx = tid & 15;
    const int lr = tid >> 2, lk = (tid & 3) * 4;

    float acc[4][4] = {};
    for (int k0 = 0; k0 < DEE; k0 += 16) {
        const float4 av = *(const float4*)(EA + (size_t)(e0 + lr) * DEE + k0 + lk);
        const float4 wv = *(const float4*)(W + (size_t)(n0 + lr) * ldw + k0 + lk);
        __syncthreads();
        As[lk+0][lr] = av.x; As[lk+1][lr] = av.y; As[lk+2][lr] = av.z; As[lk+3][lr] = av.w;
        Ws[lk+0][lr] = wv.x; Ws[lk+1][lr] = wv.y; Ws[lk+2][lr] = wv.z; Ws[lk+3][lr] = wv.w;
        __syncthreads();
        #pragma unroll
        for (int kk = 0; kk < 16; ++kk) {
            const float4 a4 = *(const float4*)&As[kk][ty*4];
            const float4 b4 = *(const float4*)&Ws[kk][tx*4];
            const float am[4] = {a4.x, a4.y, a4.z, a4.w};
            const float bm[4] = {b4.x, b4.y, b4.z, b4.w};
            #pragma unroll
            for (int i2 = 0; i2 < 4; ++i2)
                #pragma unroll
                for (int j2 = 0; j2 < 4; ++j2)
                    acc[i2][j2] = fmaf(am[i2], bm[j2], acc[i2][j2]);
        }
    }
    const float4 b4 = *(const float4*)(b1 + n0 + tx*4);
    #pragma unroll
    for (int i2 = 0; i2 < 4; ++i2) {
        const int e = e0 + ty*4 + i2;
        const int d = dst[e];
        const int sv = src[e];
        const float4 u4 = *(const float4*)(U + (size_t)d * DD + n0 + tx*4);
        const float4 v4 = *(const float4*)(V + (size_t)sv * DD + n0 + tx*4);
        float vals[4];
        vals[0] = acc[i2][0] + u4.x + v4.x + b4.x;
        vals[1] = acc[i2][1] + u4.y + v4.y + b4.y;
        vals[2] = acc[i2][2] + u4.z + v4.z + b4.z;
        vals[3] = acc[i2][3] + u4.w + v4.w + b4.w;
        float* sp = sbuf + (size_t)d * DD + n0 + tx*4;
        #pragma unroll
        for (int j2 = 0; j2 < 4; ++j2) {
            const float r = vals[j2] > 0.f ? vals[j2] : 0.f;
            atomicAdd(sp + j2, r);
        }
    }
}

__global__ __launch_bounds__(256)
void count_deg(const int* __restrict__ dst, float* __restrict__ deg) {
    const int e = blockIdx.x * 256 + threadIdx.x;
    if (e < NED) atomicAdd(&deg[dst[e]], 1.0f);
}

// a[v, :] += deg[v] * b2[:]
__global__ __launch_bounds__(256)
void add_deg_bias(float* __restrict__ a, const float* __restrict__ deg,
                  const float* __restrict__ b2) {
    const int t = blockIdx.x * 256 + threadIdx.x;  // N*64 threads
    const int v = t >> 6, q = (t & 63) * 4;
    const float dv = deg[v];
    const float4 b4 = *(const float4*)(b2 + q);
    float4 av = *(float4*)(a + (size_t)v * DD + q);
    av.x += dv * b4.x; av.y += dv * b4.y; av.z += dv * b4.z; av.w += dv * b4.w;
    *(float4*)(a + (size_t)v * DD + q) = av;
}

__device__ __forceinline__ float sigf(float x) { return 1.0f / (1.0f + expf(-x)); }

__global__ __launch_bounds__(256)
void lstm_update(const float* __restrict__ gates, float* __restrict__ c,
                 float* __restrict__ h) {
    const int t = blockIdx.x * 256 + threadIdx.x;  // N*64 threads
    const int v = t >> 6, q = (t & 63) * 4;
    const float4 ig = *(const float4*)(gates + (size_t)v * 1024 + q);
    const float4 fg = *(const float4*)(gates + (size_t)v * 1024 + 256 + q);
    const float4 gg = *(const float4*)(gates + (size_t)v * 1024 + 512 + q);
    const float4 og = *(const float4*)(gates + (size_t)v * 1024 + 768 + q);
    float4 cc = *(float4*)(c + (size_t)v * DD + q);
    float4 hh;
    cc.x = sigf(fg.x) * cc.x + sigf(ig.x) * tanhf(gg.x);
    cc.y = sigf(fg.y) * cc.y + sigf(ig.y) * tanhf(gg.y);
    cc.z = sigf(fg.z) * cc.z + sigf(ig.z) * tanhf(gg.z);
    cc.w = sigf(fg.w) * cc.w + sigf(ig.w) * tanhf(gg.w);
    hh.x = sigf(og.x) * tanhf(cc.x);
    hh.y = sigf(og.y) * tanhf(cc.y);
    hh.z = sigf(og.z) * tanhf(cc.z);
    hh.w = sigf(og.w) * tanhf(cc.w);
    *(float4*)(c + (size_t)v * DD + q) = cc;
    *(float4*)(h + (size_t)v * DD + q) = hh;
}

// out[g] += sum_v sigmoid(GG[v,g]) * FF[v,g], 128 nodes per block.
__global__ __launch_bounds__(256)
void readout_reduce(const float* __restrict__ GGm, const float* __restrict__ FFm,
                    float* __restrict__ out) {
    const int g = threadIdx.x;
    const int v0 = blockIdx.x * 128;
    float acc = 0.f;
    const int vend = (v0 + 128 < NND) ? v0 + 128 : NND;
    for (int v = v0; v < vend; ++v) {
        const float gv = GGm[(size_t)v * DD + g];
        const float fv = FFm[(size_t)v * DD + g];
        acc += sigf(gv) * fv;
    }
    atomicAdd(&out[g], acc);
}

extern "C" void kernel_launch(void* const* d_in, const int* in_sizes, int n_in,
                              void* d_out, int out_size, void* d_ws, size_t ws_size,
                              hipStream_t stream) {
    const float* x         = (const float*)d_in[0];
    const float* edge_attr = (const float*)d_in[1];
    const int*   eidx      = (const int*)d_in[2];
    const float* fe1_W     = (const float*)d_in[3];
    const float* fe1_b     = (const float*)d_in[4];
    const float* fe2_W     = (const float*)d_in[5];
    const float* fe2_b     = (const float*)d_in[6];
    const float* W_ih      = (const float*)d_in[7];
    const float* W_hh      = (const float*)d_in[8];
    const float* b_ih      = (const float*)d_in[9];
    const float* b_hh      = (const float*)d_in[10];
    const float* gm_W      = (const float*)d_in[11];
    const float* gm_b      = (const float*)d_in[12];
    const float* fm_W      = (const float*)d_in[13];
    const float* fm_b      = (const float*)d_in[14];
    float* out = (float*)d_out;

    const int* src = eidx;          // edge_index[0]
    const int* dst = eidx + NED;    // edge_index[1]

    float* ws = (float*)d_ws;
    float* h     = ws;               // 5.12M floats
    float* c     = ws + 5120000;
    float* a     = ws + 10240000;
    float* s     = ws + 15360000;
    float* U     = ws + 20480000;
    float* V     = ws + 25600000;
    float* gates = ws + 15360000;    // [N,1024] overlaps s/U/V (dead by then)
    float* deg   = ws + 35840000;    // N floats

    hipMemcpyAsync(h, x, (size_t)NND * DD * 4, hipMemcpyDeviceToDevice, stream);
    hipMemsetAsync(c, 0, (size_t)NND * DD * 4, stream);
    hipMemsetAsync(deg, 0, (size_t)NND * 4, stream);
    count_deg<<<(NED + 255) / 256, 256, 0, stream>>>(dst, deg);

    const dim3 gN((NND + 63) / 64, 4);
    const dim3 gE(NED / 64, 4);
    const dim3 gG((NND + 63) / 64, 16);

    for (int i = 0; i < 2; ++i) {
        const float* W1 = fe1_W + (size_t)i * 256 * 640;
        // U = h @ Wdst^T ; V = h @ Wsrc^T
        gemm_atw<false,false><<<gN, 256, 0, stream>>>(h, DD, W1,       640, nullptr, U, DD, NND, DD);
        gemm_atw<false,false><<<gN, 256, 0, stream>>>(h, DD, W1 + 256, 640, nullptr, V, DD, NND, DD);
        hipMemsetAsync(s, 0, (size_t)NND * DD * 4, stream);
        // per-edge: s[dst] += ReLU(EA@We^T + U[dst] + V[src] + b1)
        edge_msg<<<gE, 256, 0, stream>>>(edge_attr, W1 + 512, 640, fe1_b + (size_t)i * 256,
                                         U, V, src, dst, s);
        // a = s @ W2^T ; a += deg * b2
        gemm_atw<false,false><<<gN, 256, 0, stream>>>(s, DD, fe2_W + (size_t)i * 65536, 256,
                                                      nullptr, a, DD, NND, DD);
        add_deg_bias<<<5000, 256, 0, stream>>>(a, deg, fe2_b + (size_t)i * 256);
        // gates = h @ W_ih^T + b_ih + a @ W_hh^T + b_hh
        gemm_atw<false,true><<<gG, 256, 0, stream>>>(h, DD, W_ih + (size_t)i * 262144, 256,
                                                     b_ih + (size_t)i * 1024, gates, 1024, NND, DD);
        gemm_atw<true,true><<<gG, 256, 0, stream>>>(a, DD, W_hh + (size_t)i * 262144, 256,
                                                    b_hh + (size_t)i * 1024, gates, 1024, NND, DD);
        lstm_update<<<5000, 256, 0, stream>>>(gates, c, h);
    }

    // readout: GG = h@gm^T+gm_b (into U), FF = h@fm^T+fm_b (into V)
    gemm_atw<false,true><<<gN, 256, 0, stream>>>(h, DD, gm_W, 256, gm_b, U, DD, NND, DD);
    gemm_atw<false,true><<<gN, 256, 0, stream>>>(h, DD, fm_W, 256, fm_b, V, DD, NND, DD);
    hipMemsetAsync(out, 0, 256 * 4, stream);
    readout_reduce<<<(NND + 127) / 128, 256, 0, stream>>>(U, V, out);
}

// Round 2
// 1979.902 us; speedup vs baseline: 1.6589x; 1.6589x over previous
//
#include <hip/hip_runtime.h>
#include <hip/hip_bf16.h>
#include <math.h>

#define NND 20000
#define NED 320000
#define DD  256
#define DEE 128

// ---------------------------------------------------------------------------
// Generic tiled fp32 GEMM: C[M, NO] = (ACCUM ? C : 0) + A[M,K] @ W^T (+ bias)
// A row-major with leading dim lda; W row-major [NO, ldw] (first K cols used).
// Tile 64x64, BK=16, 256 threads, 4x4 per thread.
// ---------------------------------------------------------------------------
template<bool ACCUM, bool BIAS>
__global__ __launch_bounds__(256)
void gemm_atw(const float* __restrict__ A, int lda,
              const float* __restrict__ W, int ldw,
              const float* __restrict__ bias,
              float* __restrict__ C, int ldc,
              int M, int K) {
    __shared__ float As[16][68];
    __shared__ float Ws[16][68];
    const int m0 = blockIdx.x * 64;
    const int n0 = blockIdx.y * 64;
    const int tid = threadIdx.x;
    const int ty = tid >> 4, tx = tid & 15;
    const int lr = tid >> 2, lk = (tid & 3) * 4;

    float acc[4][4] = {};
    for (int k0 = 0; k0 < K; k0 += 16) {
        int ar = m0 + lr; if (ar >= M) ar = M - 1;
        const float4 av = *(const float4*)(A + (size_t)ar * lda + k0 + lk);
        const float4 wv = *(const float4*)(W + (size_t)(n0 + lr) * ldw + k0 + lk);
        __syncthreads();
        As[lk+0][lr] = av.x; As[lk+1][lr] = av.y; As[lk+2][lr] = av.z; As[lk+3][lr] = av.w;
        Ws[lk+0][lr] = wv.x; Ws[lk+1][lr] = wv.y; Ws[lk+2][lr] = wv.z; Ws[lk+3][lr] = wv.w;
        __syncthreads();
        #pragma unroll
        for (int kk = 0; kk < 16; ++kk) {
            const float4 a4 = *(const float4*)&As[kk][ty*4];
            const float4 b4 = *(const float4*)&Ws[kk][tx*4];
            const float am[4] = {a4.x, a4.y, a4.z, a4.w};
            const float bm[4] = {b4.x, b4.y, b4.z, b4.w};
            #pragma unroll
            for (int i2 = 0; i2 < 4; ++i2)
                #pragma unroll
                for (int j2 = 0; j2 < 4; ++j2)
                    acc[i2][j2] = fmaf(am[i2], bm[j2], acc[i2][j2]);
        }
    }
    float4 bv = {0.f, 0.f, 0.f, 0.f};
    if (BIAS) bv = *(const float4*)(bias + n0 + tx*4);
    #pragma unroll
    for (int i2 = 0; i2 < 4; ++i2) {
        const int row = m0 + ty*4 + i2;
        if (row >= M) continue;
        float* cp = C + (size_t)row * ldc + n0 + tx*4;
        float4 o = {0.f, 0.f, 0.f, 0.f};
        if (ACCUM) o = *(const float4*)cp;
        float4 r;
        r.x = acc[i2][0] + bv.x + o.x;
        r.y = acc[i2][1] + bv.y + o.y;
        r.z = acc[i2][2] + bv.z + o.z;
        r.w = acc[i2][3] + bv.w + o.w;
        *(float4*)cp = r;
    }
}

// ---------------------------------------------------------------------------
// EW[p, :] = edge_attr[perm[p0+p], :] @ We^T  for p in [0, rows)
// We rows are fe1_W[i] + 512 (the edge_attr column block), ld 640, K=128.
// ---------------------------------------------------------------------------
__global__ __launch_bounds__(256)
void gemm_ew(const float* __restrict__ EA, const int* __restrict__ perm,
             int p0, int rows,
             const float* __restrict__ W,
             float* __restrict__ EW) {
    __shared__ float As[16][68];
    __shared__ float Ws[16][68];
    const int m0 = blockIdx.x * 64;
    const int n0 = blockIdx.y * 64;
    const int tid = threadIdx.x;
    const int ty = tid >> 4, tx = tid & 15;
    const int lr = tid >> 2, lk = (tid & 3) * 4;

    int pr = m0 + lr; if (pr >= rows) pr = rows - 1;
    const int eid = perm[p0 + pr];
    const float* arow = EA + (size_t)eid * DEE;

    float acc[4][4] = {};
    for (int k0 = 0; k0 < DEE; k0 += 16) {
        const float4 av = *(const float4*)(arow + k0 + lk);
        const float4 wv = *(const float4*)(W + (size_t)(n0 + lr) * 640 + k0 + lk);
        __syncthreads();
        As[lk+0][lr] = av.x; As[lk+1][lr] = av.y; As[lk+2][lr] = av.z; As[lk+3][lr] = av.w;
        Ws[lk+0][lr] = wv.x; Ws[lk+1][lr] = wv.y; Ws[lk+2][lr] = wv.z; Ws[lk+3][lr] = wv.w;
        __syncthreads();
        #pragma unroll
        for (int kk = 0; kk < 16; ++kk) {
            const float4 a4 = *(const float4*)&As[kk][ty*4];
            const float4 b4 = *(const float4*)&Ws[kk][tx*4];
            const float am[4] = {a4.x, a4.y, a4.z, a4.w};
            const float bm[4] = {b4.x, b4.y, b4.z, b4.w};
            #pragma unroll
            for (int i2 = 0; i2 < 4; ++i2)
                #pragma unroll
                for (int j2 = 0; j2 < 4; ++j2)
                    acc[i2][j2] = fmaf(am[i2], bm[j2], acc[i2][j2]);
        }
    }
    #pragma unroll
    for (int i2 = 0; i2 < 4; ++i2) {
        const int row = m0 + ty*4 + i2;
        if (row >= rows) continue;
        float4 r = {acc[i2][0], acc[i2][1], acc[i2][2], acc[i2][3]};
        *(float4*)(EW + (size_t)row * DD + n0 + tx*4) = r;
    }
}

// ---------------------------------------------------------------------------
// Per-node gather-reduce over its CSR segment intersected with [p0, p1):
//   s[v, t] (+)= sum_p ReLU(EW[p-p0, t] + V[srcS[p], t] + U[v, t] + b1[t])
// ---------------------------------------------------------------------------
__global__ __launch_bounds__(256)
void aggregate(const float* __restrict__ EW, const int* __restrict__ srcS,
               const int* __restrict__ off,
               const float* __restrict__ U, const float* __restrict__ V,
               const float* __restrict__ b1,
               int p0, int p1, int full, float* __restrict__ s) {
    const int v = blockIdx.x;
    const int t = threadIdx.x;
    int lo = off[v], hi = off[v + 1];
    if (lo < p0) lo = p0;
    if (hi > p1) hi = p1;
    if (!full && lo >= hi) return;
    float acc = 0.f;
    if (lo < hi) {
        const float base = U[(size_t)v * DD + t] + b1[t];
        for (int p = lo; p < hi; ++p) {
            const int sv = srcS[p];
            const float val = EW[(size_t)(p - p0) * DD + t] + V[(size_t)sv * DD + t] + base;
            acc += val > 0.f ? val : 0.f;
        }
    }
    if (full) s[(size_t)v * DD + t] = acc;
    else      atomicAdd(&s[(size_t)v * DD + t], acc);
}

__global__ __launch_bounds__(256)
void count_deg(const int* __restrict__ dst, int* __restrict__ deg) {
    const int e = blockIdx.x * 256 + threadIdx.x;
    if (e < NED) atomicAdd(&deg[dst[e]], 1);
}

// single-block exclusive scan over deg -> off, cursor; off[NND] = total
__global__ __launch_bounds__(256)
void scan_offsets(const int* __restrict__ deg, int* __restrict__ off,
                  int* __restrict__ cursor) {
    __shared__ int buf[256];
    const int t = threadIdx.x;
    int carry = 0;
    for (int base = 0; base < NND; base += 256) {
        const int v = (base + t < NND) ? deg[base + t] : 0;
        buf[t] = v;
        __syncthreads();
        for (int o = 1; o < 256; o <<= 1) {
            int y = (t >= o) ? buf[t - o] : 0;
            __syncthreads();
            buf[t] += y;
            __syncthreads();
        }
        const int incl = buf[t];
        if (base + t < NND) {
            const int ex = carry + incl - v;
            off[base + t] = ex;
            cursor[base + t] = ex;
        }
        carry += buf[255];
        __syncthreads();
    }
    if (t == 0) off[NND] = carry;
}

__global__ __launch_bounds__(256)
void scatter_edges(const int* __restrict__ dst, const int* __restrict__ src,
                   int* __restrict__ cursor, int* __restrict__ perm,
                   int* __restrict__ srcS) {
    const int e = blockIdx.x * 256 + threadIdx.x;
    if (e < NED) {
        const int d = dst[e];
        const int p = atomicAdd(&cursor[d], 1);
        perm[p] = e;
        srcS[p] = src[e];
    }
}

// a[v, :] += deg[v] * b2[:]
__global__ __launch_bounds__(256)
void add_deg_bias(float* __restrict__ a, const int* __restrict__ deg,
                  const float* __restrict__ b2) {
    const int t = blockIdx.x * 256 + threadIdx.x;  // N*64 threads
    const int v = t >> 6, q = (t & 63) * 4;
    const float dv = (float)deg[v];
    const float4 b4 = *(const float4*)(b2 + q);
    float4 av = *(float4*)(a + (size_t)v * DD + q);
    av.x += dv * b4.x; av.y += dv * b4.y; av.z += dv * b4.z; av.w += dv * b4.w;
    *(float4*)(a + (size_t)v * DD + q) = av;
}

__device__ __forceinline__ float sigf(float x) { return 1.0f / (1.0f + expf(-x)); }

// nodes are relative to the passed base pointers; gates stride 1024
__global__ __launch_bounds__(256)
void lstm_update(const float* __restrict__ gates, float* __restrict__ c,
                 float* __restrict__ h) {
    const int t = blockIdx.x * 256 + threadIdx.x;
    const int v = t >> 6, q = (t & 63) * 4;
    const float4 ig = *(const float4*)(gates + (size_t)v * 1024 + q);
    const float4 fg = *(const float4*)(gates + (size_t)v * 1024 + 256 + q);
    const float4 gg = *(const float4*)(gates + (size_t)v * 1024 + 512 + q);
    const float4 og = *(const float4*)(gates + (size_t)v * 1024 + 768 + q);
    float4 cc = *(float4*)(c + (size_t)v * DD + q);
    float4 hh;
    cc.x = sigf(fg.x) * cc.x + sigf(ig.x) * tanhf(gg.x);
    cc.y = sigf(fg.y) * cc.y + sigf(ig.y) * tanhf(gg.y);
    cc.z = sigf(fg.z) * cc.z + sigf(ig.z) * tanhf(gg.z);
    cc.w = sigf(fg.w) * cc.w + sigf(ig.w) * tanhf(gg.w);
    hh.x = sigf(og.x) * tanhf(cc.x);
    hh.y = sigf(og.y) * tanhf(cc.y);
    hh.z = sigf(og.z) * tanhf(cc.z);
    hh.w = sigf(og.w) * tanhf(cc.w);
    *(float4*)(c + (size_t)v * DD + q) = cc;
    *(float4*)(h + (size_t)v * DD + q) = hh;
}

// out[g] += sum_v sigmoid(GG[v,g]) * FF[v,g]
__global__ __launch_bounds__(256)
void readout_reduce(const float* __restrict__ GGm, const float* __restrict__ FFm,
                    float* __restrict__ out) {
    const int g = threadIdx.x;
    const int v0 = blockIdx.x * 128;
    float acc = 0.f;
    const int vend = (v0 + 128 < NND) ? v0 + 128 : NND;
    for (int v = v0; v < vend; ++v) {
        const float gv = GGm[(size_t)v * DD + g];
        const float fv = FFm[(size_t)v * DD + g];
        acc += sigf(gv) * fv;
    }
    atomicAdd(&out[g], acc);
}

extern "C" void kernel_launch(void* const* d_in, const int* in_sizes, int n_in,
                              void* d_out, int out_size, void* d_ws, size_t ws_size,
                              hipStream_t stream) {
    const float* x         = (const float*)d_in[0];
    const float* edge_attr = (const float*)d_in[1];
    const int*   eidx      = (const int*)d_in[2];
    const float* fe1_W     = (const float*)d_in[3];
    const float* fe1_b     = (const float*)d_in[4];
    const float* fe2_W     = (const float*)d_in[5];
    const float* fe2_b     = (const float*)d_in[6];
    const float* W_ih      = (const float*)d_in[7];
    const float* W_hh      = (const float*)d_in[8];
    const float* b_ih      = (const float*)d_in[9];
    const float* b_hh      = (const float*)d_in[10];
    const float* gm_W      = (const float*)d_in[11];
    const float* gm_b      = (const float*)d_in[12];
    const float* fm_W      = (const float*)d_in[13];
    const float* fm_b      = (const float*)d_in[14];
    float* out = (float*)d_out;

    const int* src = eidx;          // edge_index[0]
    const int* dst = eidx + NED;    // edge_index[1]

    // ---- workspace layout (floats) -----------------------------------------
    // h      [0        , 5.12M)
    // c      [5.12M    , 10.24M)
    // s      [10.24M   , 15.36M)
    // U      [15.36M   , 20.48M)
    // V      [20.48M   , 25.60M)
    // gatesH [10.24M   , 20.48M)  half-N x 1024; overlaps s,U (dead by then)
    // a      [25.60M   , 30.72M)
    // ints   [30.72M   , ~31.42M) deg/off/perm/srcS/cursor
    // EW     [31.42M+  , ...)     chunked; >=10000-row fallback fits 136MB
    float* ws = (float*)d_ws;
    float* h      = ws;
    float* c      = ws + 5120000L;
    float* s      = ws + 10240000L;
    float* U      = ws + 15360000L;
    float* V      = ws + 20480000L;
    float* gatesH = ws + 10240000L;
    float* a      = ws + 25600000L;
    int*   ib     = (int*)(ws + 30720000L);
    int* deg    = ib;                 // 20000
    int* off    = ib + 20000;         // 20001
    int* perm   = ib + 40001;         // 320000
    int* srcS   = ib + 360001;        // 320000
    int* cursor = ib + 680001;        // 20000  -> ends at ib+700001

    const long ew_off = 30720000L + 700016L;   // float offset, aligned
    float* EW = ws + ew_off;
    const long total_f = (long)(ws_size / sizeof(float));
    long avail_rows = (total_f - ew_off) / 256;
    long cap = avail_rows;
    if (cap > NED) cap = NED;
    if (cap < 10000) cap = 10000;     // safe: 10000 rows ends at ~135.9 MB
    const int full = (cap >= NED) ? 1 : 0;

    // ---- one-time: h=x, c=0, CSR build -------------------------------------
    hipMemcpyAsync(h, x, (size_t)NND * DD * 4, hipMemcpyDeviceToDevice, stream);
    hipMemsetAsync(c, 0, (size_t)NND * DD * 4, stream);
    hipMemsetAsync(deg, 0, (size_t)NND * 4, stream);
    count_deg<<<(NED + 255) / 256, 256, 0, stream>>>(dst, deg);
    scan_offsets<<<1, 256, 0, stream>>>(deg, off, cursor);
    scatter_edges<<<(NED + 255) / 256, 256, 0, stream>>>(dst, src, cursor, perm, srcS);

    const dim3 gN((NND + 63) / 64, 4);
    const dim3 gH((10000 + 63) / 64, 16);

    for (int i = 0; i < 2; ++i) {
        const float* W1 = fe1_W + (size_t)i * 256 * 640;
        // U = h @ Wdst^T ; V = h @ Wsrc^T
        gemm_atw<false,false><<<gN, 256, 0, stream>>>(h, DD, W1,       640, nullptr, U, DD, NND, DD);
        gemm_atw<false,false><<<gN, 256, 0, stream>>>(h, DD, W1 + 256, 640, nullptr, V, DD, NND, DD);
        if (!full) hipMemsetAsync(s, 0, (size_t)NND * DD * 4, stream);
        // chunked: EW = EA[perm] @ We^T, then gather-reduce into s
        for (long p0 = 0; p0 < NED; p0 += cap) {
            const long p1 = (p0 + cap < NED) ? p0 + cap : NED;
            const int rows = (int)(p1 - p0);
            const dim3 ge((rows + 63) / 64, 4);
            gemm_ew<<<ge, 256, 0, stream>>>(edge_attr, perm, (int)p0, rows, W1 + 512, EW);
            aggregate<<<NND, 256, 0, stream>>>(EW, srcS, off, U, V,
                                               fe1_b + (size_t)i * 256,
                                               (int)p0, (int)p1, full, s);
        }
        // a = s @ W2^T ; a += deg * b2
        gemm_atw<false,false><<<gN, 256, 0, stream>>>(s, DD, fe2_W + (size_t)i * 65536, 256,
                                                      nullptr, a, DD, NND, DD);
        add_deg_bias<<<5000, 256, 0, stream>>>(a, deg, fe2_b + (size_t)i * 256);
        // gates in two node-halves (gatesH region is only half-N x 1024)
        for (int half = 0; half < 2; ++half) {
            const long nb = (long)half * 10000 * DD;
            gemm_atw<false,true><<<gH, 256, 0, stream>>>(h + nb, DD,
                W_ih + (size_t)i * 262144, 256, b_ih + (size_t)i * 1024,
                gatesH, 1024, 10000, DD);
            gemm_atw<true,true><<<gH, 256, 0, stream>>>(a + nb, DD,
                W_hh + (size_t)i * 262144, 256, b_hh + (size_t)i * 1024,
                gatesH, 1024, 10000, DD);
            lstm_update<<<2500, 256, 0, stream>>>(gatesH, c + nb, h + nb);
        }
    }

    // readout: GG = h@gm^T+gm_b (into U), FF = h@fm^T+fm_b (into V)
    gemm_atw<false,true><<<gN, 256, 0, stream>>>(h, DD, gm_W, 256, gm_b, U, DD, NND, DD);
    gemm_atw<false,true><<<gN, 256, 0, stream>>>(h, DD, fm_W, 256, fm_b, V, DD, NND, DD);
    hipMemsetAsync(out, 0, 256 * 4, stream);
    readout_reduce<<<(NND + 127) / 128, 256, 0, stream>>>(U, V, out);
}

// Round 3
// 947.517 us; speedup vs baseline: 3.4665x; 2.0896x over previous
//
#include <hip/hip_runtime.h>
#include <hip/hip_bf16.h>
#include <math.h>

#define NND 20000
#define NED 320000
#define DD  256
#define DEE 128

typedef __attribute__((ext_vector_type(8))) short bf16x8;
typedef __attribute__((ext_vector_type(4))) float f32x4;

__device__ __forceinline__ float b2f(unsigned short u) {
    union { float f; unsigned int i; } x; x.i = ((unsigned int)u) << 16; return x.f;
}
__device__ __forceinline__ unsigned short f2b(float f) {
    union { float f; unsigned int i; } x; x.f = f;
    unsigned int r = x.i + 0x7fffu + ((x.i >> 16) & 1u);
    return (unsigned short)(r >> 16);
}

__device__ __forceinline__ void gload_lds16(const void* g, void* l) {
    __builtin_amdgcn_global_load_lds((const __attribute__((address_space(1))) void*)g,
                                     (__attribute__((address_space(3))) void*)l, 16, 0, 0);
}

// ---------------------------------------------------------------------------
// bf16 MFMA GEMM: C[M,N] = A[M,K](bf16, lda) @ W[N,K](bf16, packed ldw=K)^T
// 128x128 tile, BK=32, 256 threads (4 waves in 2x2), 16x16x32 MFMA.
// A rows clamped for M-tail; N, K multiples of 128/32. ldc == N.
// ---------------------------------------------------------------------------
template<bool OUTBF16, bool BIAS>
__global__ __launch_bounds__(256)
void mgemm(const unsigned short* __restrict__ A, int lda,
           const unsigned short* __restrict__ W,
           const float* __restrict__ bias,
           void* __restrict__ Cv, int M, int N, int K) {
    __shared__ unsigned short As[128 * 32];
    __shared__ unsigned short Bs[128 * 32];
    const int m0 = blockIdx.x * 128;
    const int n0 = blockIdx.y * 128;
    const int tid = threadIdx.x;
    const int wid = tid >> 6, lane = tid & 63;
    const int wr = wid >> 1, wc = wid & 1;
    const int sr = tid >> 2;          // staging row within 64-row half
    const int sc = (tid & 3) * 8;     // staging k-element offset

    int ra0 = m0 + sr;      if (ra0 >= M) ra0 = M - 1;
    int ra1 = m0 + 64 + sr; if (ra1 >= M) ra1 = M - 1;
    const int rb0 = n0 + sr, rb1 = n0 + 64 + sr;

    char* lA = (char*)As + wid * 1024;
    char* lB = (char*)Bs + wid * 1024;

    f32x4 acc[4][4] = {};
    for (int k0 = 0; k0 < K; k0 += 32) {
        __syncthreads();
        gload_lds16(A + (size_t)ra0 * lda + k0 + sc, lA);
        gload_lds16(A + (size_t)ra1 * lda + k0 + sc, lA + 4096);
        gload_lds16(W + (size_t)rb0 * K + k0 + sc, lB);
        gload_lds16(W + (size_t)rb1 * K + k0 + sc, lB + 4096);
        __syncthreads();

        bf16x8 af[4], bf[4];
        const int ar = wr * 64 + (lane & 15);
        const int br = wc * 64 + (lane & 15);
        const int ke = (lane >> 4) * 8;
        #pragma unroll
        for (int m = 0; m < 4; ++m) af[m] = *(const bf16x8*)&As[(ar + m * 16) * 32 + ke];
        #pragma unroll
        for (int n = 0; n < 4; ++n) bf[n] = *(const bf16x8*)&Bs[(br + n * 16) * 32 + ke];
        #pragma unroll
        for (int m = 0; m < 4; ++m)
            #pragma unroll
            for (int n = 0; n < 4; ++n)
                acc[m][n] = __builtin_amdgcn_mfma_f32_16x16x32_bf16(af[m], bf[n], acc[m][n], 0, 0, 0);
    }

    // C/D layout: col = lane&15, row = (lane>>4)*4 + reg
    const int r0 = m0 + wr * 64 + (lane >> 4) * 4;
    const int c0 = n0 + wc * 64 + (lane & 15);
    #pragma unroll
    for (int n = 0; n < 4; ++n) {
        const int col = c0 + n * 16;
        const float bv = BIAS ? bias[col] : 0.f;
        #pragma unroll
        for (int m = 0; m < 4; ++m) {
            const int row = r0 + m * 16;
            #pragma unroll
            for (int j = 0; j < 4; ++j) {
                if (row + j < M) {
                    const float v = acc[m][n][j] + bv;
                    if (OUTBF16) ((unsigned short*)Cv)[(size_t)(row + j) * N + col] = f2b(v);
                    else         ((float*)Cv)[(size_t)(row + j) * N + col] = v;
                }
            }
        }
    }
}

// fp32 block -> bf16 block copy/cast: dst[(dr+r)*ldd + dc + c] = src[r*lds + col0 + c]
__global__ __launch_bounds__(256)
void cast_blk(const float* __restrict__ src, int lds_, int col0,
              int rows, int cols, unsigned short* __restrict__ dst,
              int ldd, int dr, int dc) {
    const long g = ((long)blockIdx.x * 256 + threadIdx.x) * 4;
    if (g >= (long)rows * cols) return;
    const int r = (int)(g / cols), cc = (int)(g % cols);
    const float4 v = *(const float4*)(src + (size_t)r * lds_ + col0 + cc);
    unsigned short* d = dst + (size_t)(dr + r) * ldd + dc + cc;
    d[0] = f2b(v.x); d[1] = f2b(v.y); d[2] = f2b(v.z); d[3] = f2b(v.w);
}

// gather edge_attr rows in dst-sorted order, cast to bf16
__global__ __launch_bounds__(256)
void gcvt(const float* __restrict__ EA, const int* __restrict__ perm,
          int p0, int rows, unsigned short* __restrict__ EB) {
    const int g = blockIdx.x * 256 + threadIdx.x;
    if (g >= rows * 32) return;
    const int r = g >> 5, j = (g & 31) * 4;
    const int e = perm[p0 + r];
    const float4 v = *(const float4*)(EA + (size_t)e * DEE + j);
    unsigned short* d = EB + (size_t)r * DEE + j;
    d[0] = f2b(v.x); d[1] = f2b(v.y); d[2] = f2b(v.z); d[3] = f2b(v.w);
}

// per-node gather-reduce: s[v,t] (+)= sum_p ReLU(EW[p,t] + V[src[p],t] + U[v,t] + b1[t])
__global__ __launch_bounds__(256)
void aggregate(const unsigned short* __restrict__ EW, const int* __restrict__ srcS,
               const int* __restrict__ off, const unsigned short* __restrict__ UV,
               const float* __restrict__ b1, int p0, int p1, int full,
               float* __restrict__ s) {
    const int v = blockIdx.x, t = threadIdx.x;
    int lo = off[v], hi = off[v + 1];
    if (lo < p0) lo = p0;
    if (hi > p1) hi = p1;
    if (!full && lo >= hi) return;
    float acc = 0.f;
    if (lo < hi) {
        const float base = b2f(UV[(size_t)v * 512 + t]) + b1[t];
        for (int p = lo; p < hi; ++p) {
            const int sv = srcS[p];
            const float val = b2f(EW[(size_t)(p - p0) * DD + t])
                            + b2f(UV[(size_t)sv * 512 + 256 + t]) + base;
            acc += val > 0.f ? val : 0.f;
        }
    }
    if (full) s[(size_t)v * DD + t] = acc;
    else      atomicAdd(&s[(size_t)v * DD + t], acc);
}

__global__ __launch_bounds__(256)
void count_deg(const int* __restrict__ dst, int* __restrict__ deg) {
    const int e = blockIdx.x * 256 + threadIdx.x;
    if (e < NED) atomicAdd(&deg[dst[e]], 1);
}

__global__ __launch_bounds__(256)
void scan_offsets(const int* __restrict__ deg, int* __restrict__ off,
                  int* __restrict__ cursor) {
    __shared__ int buf[256];
    const int t = threadIdx.x;
    int carry = 0;
    for (int base = 0; base < NND; base += 256) {
        const int v = (base + t < NND) ? deg[base + t] : 0;
        buf[t] = v;
        __syncthreads();
        for (int o = 1; o < 256; o <<= 1) {
            int y = (t >= o) ? buf[t - o] : 0;
            __syncthreads();
            buf[t] += y;
            __syncthreads();
        }
        const int incl = buf[t];
        if (base + t < NND) {
            const int ex = carry + incl - v;
            off[base + t] = ex;
            cursor[base + t] = ex;
        }
        carry += buf[255];
        __syncthreads();
    }
    if (t == 0) off[NND] = carry;
}

__global__ __launch_bounds__(256)
void scatter_edges(const int* __restrict__ dst, const int* __restrict__ src,
                   int* __restrict__ cursor, int* __restrict__ perm,
                   int* __restrict__ srcS) {
    const int e = blockIdx.x * 256 + threadIdx.x;
    if (e < NED) {
        const int d = dst[e];
        const int p = atomicAdd(&cursor[d], 1);
        perm[p] = e;
        srcS[p] = src[e];
    }
}

// hab a-part = bf16(a + deg*b2)
__global__ __launch_bounds__(256)
void cvt_a(const float* __restrict__ a, const int* __restrict__ deg,
           const float* __restrict__ b2, unsigned short* __restrict__ hab) {
    const int t = blockIdx.x * 256 + threadIdx.x;
    const int v = t >> 6, q = (t & 63) * 4;
    const float dv = (float)deg[v];
    const float4 b4 = *(const float4*)(b2 + q);
    const float4 av = *(const float4*)(a + (size_t)v * DD + q);
    unsigned short* d = hab + (size_t)v * 512 + 256 + q;
    d[0] = f2b(av.x + dv * b4.x); d[1] = f2b(av.y + dv * b4.y);
    d[2] = f2b(av.z + dv * b4.z); d[3] = f2b(av.w + dv * b4.w);
}

__device__ __forceinline__ float sigf(float x) { return 1.0f / (1.0f + expf(-x)); }

// gates bf16 [v][1024] (i,f,g,o); c fp32; h written as bf16 into hab h-part
__global__ __launch_bounds__(256)
void lstm_update(const unsigned short* __restrict__ gates, float* __restrict__ c,
                 unsigned short* __restrict__ hab) {
    const int t = blockIdx.x * 256 + threadIdx.x;
    const int v = t >> 6, q = (t & 63) * 4;
    const unsigned short* gp = gates + (size_t)v * 1024;
    const ushort4 i4 = *(const ushort4*)(gp + q);
    const ushort4 f4 = *(const ushort4*)(gp + 256 + q);
    const ushort4 g4 = *(const ushort4*)(gp + 512 + q);
    const ushort4 o4 = *(const ushort4*)(gp + 768 + q);
    float4 cc = *(float4*)(c + (size_t)v * DD + q);
    float nc[4], nh[4];
    const float ig[4] = {b2f(i4.x), b2f(i4.y), b2f(i4.z), b2f(i4.w)};
    const float fg[4] = {b2f(f4.x), b2f(f4.y), b2f(f4.z), b2f(f4.w)};
    const float gg[4] = {b2f(g4.x), b2f(g4.y), b2f(g4.z), b2f(g4.w)};
    const float og[4] = {b2f(o4.x), b2f(o4.y), b2f(o4.z), b2f(o4.w)};
    const float co[4] = {cc.x, cc.y, cc.z, cc.w};
    #pragma unroll
    for (int j = 0; j < 4; ++j) {
        nc[j] = sigf(fg[j]) * co[j] + sigf(ig[j]) * tanhf(gg[j]);
        nh[j] = sigf(og[j]) * tanhf(nc[j]);
    }
    cc.x = nc[0]; cc.y = nc[1]; cc.z = nc[2]; cc.w = nc[3];
    *(float4*)(c + (size_t)v * DD + q) = cc;
    unsigned short* d = hab + (size_t)v * 512 + q;
    d[0] = f2b(nh[0]); d[1] = f2b(nh[1]); d[2] = f2b(nh[2]); d[3] = f2b(nh[3]);
}

// bsum[0:2048] = b_ih + b_hh (both steps); gfb[0:256]=gm_b, [256:512]=fm_b
__global__ __launch_bounds__(256)
void prep_bias(const float* __restrict__ b_ih, const float* __restrict__ b_hh,
               const float* __restrict__ gm_b, const float* __restrict__ fm_b,
               float* __restrict__ bsum, float* __restrict__ gfb) {
    const int t = blockIdx.x * 256 + threadIdx.x;
    if (t < 2048) bsum[t] = b_ih[t] + b_hh[t];
    else if (t < 2304) gfb[t - 2048] = gm_b[t - 2048];
    else if (t < 2560) gfb[t - 2048] = fm_b[t - 2304];
}

// out[g] += sum_v sigmoid(RO[v,g]) * RO[v,256+g]
__global__ __launch_bounds__(256)
void readout_reduce(const float* __restrict__ RO, float* __restrict__ out) {
    const int g = threadIdx.x;
    const int v0 = blockIdx.x * 128;
    float acc = 0.f;
    const int vend = (v0 + 128 < NND) ? v0 + 128 : NND;
    for (int v = v0; v < vend; ++v) {
        acc += sigf(RO[(size_t)v * 512 + g]) * RO[(size_t)v * 512 + 256 + g];
    }
    atomicAdd(&out[g], acc);
}

extern "C" void kernel_launch(void* const* d_in, const int* in_sizes, int n_in,
                              void* d_out, int out_size, void* d_ws, size_t ws_size,
                              hipStream_t stream) {
    const float* x         = (const float*)d_in[0];
    const float* edge_attr = (const float*)d_in[1];
    const int*   eidx      = (const int*)d_in[2];
    const float* fe1_W     = (const float*)d_in[3];
    const float* fe1_b     = (const float*)d_in[4];
    const float* fe2_W     = (const float*)d_in[5];
    const float* fe2_b     = (const float*)d_in[6];
    const float* W_ih      = (const float*)d_in[7];
    const float* W_hh      = (const float*)d_in[8];
    const float* b_ih      = (const float*)d_in[9];
    const float* b_hh      = (const float*)d_in[10];
    const float* gm_W      = (const float*)d_in[11];
    const float* gm_b      = (const float*)d_in[12];
    const float* fm_W      = (const float*)d_in[13];
    const float* fm_b      = (const float*)d_in[14];
    float* out = (float*)d_out;

    const int* src = eidx;
    const int* dst = eidx + NED;

    // ---- workspace layout (float offsets) ----------------------------------
    // R region [0, 15.36M): UVb bf16 [0,5.12M) | s f32 [5.12M,10.24M) |
    //   a f32 [10.24M,15.36M); gates bf16 overlaps [0,10.24M) (UV,s dead);
    //   RO f32 overlaps [0,10.24M) at the end.
    float* ws = (float*)d_ws;
    unsigned short* UVb    = (unsigned short*)ws;
    float*          s      = ws + 5120000L;
    float*          a      = ws + 10240000L;
    unsigned short* gatesb = (unsigned short*)ws;
    float*          RO     = ws;
    float*          c      = ws + 15360000L;
    unsigned short* hab    = (unsigned short*)(ws + 20480000L);
    unsigned short* sb     = (unsigned short*)(ws + 25600000L);
    unsigned short* wb     = (unsigned short*)(ws + 28160000L);   // 1.64M bf16
    float*          bias_f = ws + 29060000L;                      // 2560 f32
    int*            ib     = (int*)(ws + 29070000L);
    int* deg    = ib;
    int* off    = ib + 20000;
    int* perm   = ib + 40001;
    int* srcS   = ib + 360001;
    int* cursor = ib + 680001;                                    // ends 700001

    const long CHUNK0 = 29800000L;
    const long total_f = (long)(ws_size / sizeof(float));
    long cap = ((total_f - CHUNK0) / 192) & ~127L;
    if (cap > NED) cap = NED;
    if (cap < 2560) cap = 2560;
    const int full = (cap >= NED) ? 1 : 0;
    unsigned short* EABs = (unsigned short*)(ws + CHUNK0);        // cap x 128 bf16
    unsigned short* EWb  = (unsigned short*)(ws + CHUNK0 + cap * 64);  // cap x 256 bf16

    // weight table offsets (bf16 elements)
    const long WUV = 0;        // [i]: 512x256  (+i*131072)
    const long WEB = 262144;   // [i]: 256x128  (+i*32768)
    const long WF2 = 327680;   // [i]: 256x256  (+i*65536)
    const long WG  = 458752;   // [i]: 1024x512 (+i*524288)
    const long WGM = 1507328;  // 512x256

    // ---- one-time setup ----------------------------------------------------
    hipMemsetAsync(c, 0, (size_t)NND * DD * 4, stream);
    hipMemsetAsync(deg, 0, (size_t)NND * 4, stream);
    count_deg<<<(NED + 255) / 256, 256, 0, stream>>>(dst, deg);
    scan_offsets<<<1, 256, 0, stream>>>(deg, off, cursor);
    scatter_edges<<<(NED + 255) / 256, 256, 0, stream>>>(dst, src, cursor, perm, srcS);
    prep_bias<<<10, 256, 0, stream>>>(b_ih, b_hh, gm_b, fm_b, bias_f, bias_f + 2048);
    // x -> hab h-part
    cast_blk<<<5000, 256, 0, stream>>>(x, 256, 0, NND, 256, hab, 512, 0, 0);
    // weights -> bf16
    for (int i = 0; i < 2; ++i) {
        const float* W1 = fe1_W + (size_t)i * 256 * 640;
        cast_blk<<<64, 256, 0, stream>>>(W1, 640, 0,   256, 256, wb + WUV + i * 131072, 256, 0, 0);
        cast_blk<<<64, 256, 0, stream>>>(W1, 640, 256, 256, 256, wb + WUV + i * 131072, 256, 256, 0);
        cast_blk<<<32, 256, 0, stream>>>(W1, 640, 512, 256, 128, wb + WEB + i * 32768, 128, 0, 0);
        cast_blk<<<64, 256, 0, stream>>>(fe2_W + (size_t)i * 65536, 256, 0, 256, 256,
                                         wb + WF2 + i * 65536, 256, 0, 0);
        cast_blk<<<256, 256, 0, stream>>>(W_ih + (size_t)i * 262144, 256, 0, 1024, 256,
                                          wb + WG + i * 524288, 512, 0, 0);
        cast_blk<<<256, 256, 0, stream>>>(W_hh + (size_t)i * 262144, 256, 0, 1024, 256,
                                          wb + WG + i * 524288, 512, 0, 256);
    }
    cast_blk<<<64, 256, 0, stream>>>(gm_W, 256, 0, 256, 256, wb + WGM, 256, 0, 0);
    cast_blk<<<64, 256, 0, stream>>>(fm_W, 256, 0, 256, 256, wb + WGM, 256, 256, 0);

    const dim3 gUV(157, 4), gF2(157, 2), gGT(157, 8), gRO(157, 4);

    for (int i = 0; i < 2; ++i) {
        // UV = hab[:, :256] @ [Wdst;Wsrc]^T   (bf16 out)
        mgemm<true, false><<<gUV, 256, 0, stream>>>(hab, 512, wb + WUV + i * 131072,
                                                    nullptr, UVb, NND, 512, 256);
        if (!full) hipMemsetAsync(s, 0, (size_t)NND * DD * 4, stream);
        for (long p0 = 0; p0 < NED; p0 += cap) {
            const long p1 = (p0 + cap < NED) ? p0 + cap : NED;
            const int rows = (int)(p1 - p0);
            gcvt<<<(rows * 32 + 255) / 256, 256, 0, stream>>>(edge_attr, perm, (int)p0, rows, EABs);
            mgemm<true, false><<<dim3((rows + 127) / 128, 2), 256, 0, stream>>>(
                EABs, 128, wb + WEB + i * 32768, nullptr, EWb, rows, 256, 128);
            aggregate<<<NND, 256, 0, stream>>>(EWb, srcS, off, UVb,
                                               fe1_b + (size_t)i * 256, (int)p0, (int)p1, full, s);
        }
        // a = s @ W2^T ; hab a-part = bf16(a + deg*b2)
        cast_blk<<<5000, 256, 0, stream>>>(s, 256, 0, NND, 256, sb, 256, 0, 0);
        mgemm<false, false><<<gF2, 256, 0, stream>>>(sb, 256, wb + WF2 + i * 65536,
                                                     nullptr, a, NND, 256, 256);
        cvt_a<<<5000, 256, 0, stream>>>(a, deg, fe2_b + (size_t)i * 256, hab);
        // gates = [h|a] @ [W_ih|W_hh]^T + (b_ih+b_hh)   (bf16 out)
        mgemm<true, true><<<gGT, 256, 0, stream>>>(hab, 512, wb + WG + i * 524288,
                                                   bias_f + (size_t)i * 1024, gatesb, NND, 1024, 512);
        lstm_update<<<5000, 256, 0, stream>>>(gatesb, c, hab);
    }

    // readout
    mgemm<false, true><<<gRO, 256, 0, stream>>>(hab, 512, wb + WGM, bias_f + 2048, RO, NND, 512, 256);
    hipMemsetAsync(out, 0, 256 * 4, stream);
    readout_reduce<<<157, 256, 0, stream>>>(RO, out);
}

// Round 4
// 893.524 us; speedup vs baseline: 3.6759x; 1.0604x over previous
//
#include <hip/hip_runtime.h>
#include <hip/hip_bf16.h>
#include <math.h>

#define NND 20000
#define NED 320000
#define DD  256
#define DEE 128

typedef __attribute__((ext_vector_type(8))) short bf16x8;
typedef __attribute__((ext_vector_type(4))) float f32x4;

__device__ __forceinline__ float b2f(unsigned short u) {
    union { float f; unsigned int i; } x; x.i = ((unsigned int)u) << 16; return x.f;
}
__device__ __forceinline__ unsigned short f2b(float f) {
    union { float f; unsigned int i; } x; x.f = f;
    unsigned int r = x.i + 0x7fffu + ((x.i >> 16) & 1u);
    return (unsigned short)(r >> 16);
}

__device__ __forceinline__ void gload_lds16(const void* g, void* l) {
    __builtin_amdgcn_global_load_lds((const __attribute__((address_space(1))) void*)g,
                                     (__attribute__((address_space(3))) void*)l, 16, 0, 0);
}

// ---------------------------------------------------------------------------
// bf16 MFMA GEMM: C[M,N] = A[M,K](bf16, lda) @ W[N,K](bf16, packed ldw=K)^T
// 128x128 tile, BK=32, 256 threads (4 waves 2x2), 16x16x32 MFMA. ldc == N.
// EDGEV: epilogue adds V[srcS[p0+row]] (UV cols 256..511) and writes bf16.
// ---------------------------------------------------------------------------
template<bool OUTBF16, bool BIAS, bool EDGEV>
__global__ __launch_bounds__(256)
void mgemm(const unsigned short* __restrict__ A, int lda,
           const unsigned short* __restrict__ W,
           const float* __restrict__ bias,
           void* __restrict__ Cv, int M, int N, int K,
           const int* __restrict__ srcS, const unsigned short* __restrict__ UV,
           int p0) {
    __shared__ unsigned short As[128 * 32];
    __shared__ unsigned short Bs[128 * 32];
    const int m0 = blockIdx.x * 128;
    const int n0 = blockIdx.y * 128;
    const int tid = threadIdx.x;
    const int wid = tid >> 6, lane = tid & 63;
    const int wr = wid >> 1, wc = wid & 1;
    const int sr = tid >> 2;
    const int sc = (tid & 3) * 8;

    int ra0 = m0 + sr;      if (ra0 >= M) ra0 = M - 1;
    int ra1 = m0 + 64 + sr; if (ra1 >= M) ra1 = M - 1;
    const int rb0 = n0 + sr, rb1 = n0 + 64 + sr;

    char* lA = (char*)As + wid * 1024;
    char* lB = (char*)Bs + wid * 1024;

    f32x4 acc[4][4] = {};
    for (int k0 = 0; k0 < K; k0 += 32) {
        __syncthreads();
        gload_lds16(A + (size_t)ra0 * lda + k0 + sc, lA);
        gload_lds16(A + (size_t)ra1 * lda + k0 + sc, lA + 4096);
        gload_lds16(W + (size_t)rb0 * K + k0 + sc, lB);
        gload_lds16(W + (size_t)rb1 * K + k0 + sc, lB + 4096);
        __syncthreads();

        bf16x8 af[4], bfr[4];
        const int ar = wr * 64 + (lane & 15);
        const int br = wc * 64 + (lane & 15);
        const int ke = (lane >> 4) * 8;
        #pragma unroll
        for (int m = 0; m < 4; ++m) af[m] = *(const bf16x8*)&As[(ar + m * 16) * 32 + ke];
        #pragma unroll
        for (int n = 0; n < 4; ++n) bfr[n] = *(const bf16x8*)&Bs[(br + n * 16) * 32 + ke];
        #pragma unroll
        for (int m = 0; m < 4; ++m)
            #pragma unroll
            for (int n = 0; n < 4; ++n)
                acc[m][n] = __builtin_amdgcn_mfma_f32_16x16x32_bf16(af[m], bfr[n], acc[m][n], 0, 0, 0);
    }

    // C/D layout: col = lane&15, row = (lane>>4)*4 + reg
    const int r0 = m0 + wr * 64 + (lane >> 4) * 4;
    const int c0 = n0 + wc * 64 + (lane & 15);
    if (EDGEV) {
        #pragma unroll
        for (int m = 0; m < 4; ++m) {
            #pragma unroll
            for (int j = 0; j < 4; ++j) {
                const int row = r0 + m * 16 + j;
                if (row < M) {
                    const int sv = srcS[p0 + row];
                    #pragma unroll
                    for (int n = 0; n < 4; ++n) {
                        const int col = c0 + n * 16;
                        const float v = acc[m][n][j] + b2f(UV[(size_t)sv * 512 + 256 + col]);
                        ((unsigned short*)Cv)[(size_t)row * N + col] = f2b(v);
                    }
                }
            }
        }
    } else {
        #pragma unroll
        for (int n = 0; n < 4; ++n) {
            const int col = c0 + n * 16;
            const float bv = BIAS ? bias[col] : 0.f;
            #pragma unroll
            for (int m = 0; m < 4; ++m) {
                const int row = r0 + m * 16;
                #pragma unroll
                for (int j = 0; j < 4; ++j) {
                    if (row + j < M) {
                        const float v = acc[m][n][j] + bv;
                        if (OUTBF16) ((unsigned short*)Cv)[(size_t)(row + j) * N + col] = f2b(v);
                        else         ((float*)Cv)[(size_t)(row + j) * N + col] = v;
                    }
                }
            }
        }
    }
}

__global__ __launch_bounds__(256)
void cast_blk(const float* __restrict__ src, int lds_, int col0,
              int rows, int cols, unsigned short* __restrict__ dst,
              int ldd, int dr, int dc) {
    const long g = ((long)blockIdx.x * 256 + threadIdx.x) * 4;
    if (g >= (long)rows * cols) return;
    const int r = (int)(g / cols), cc = (int)(g % cols);
    const float4 v = *(const float4*)(src + (size_t)r * lds_ + col0 + cc);
    unsigned short* d = dst + (size_t)(dr + r) * ldd + dc + cc;
    d[0] = f2b(v.x); d[1] = f2b(v.y); d[2] = f2b(v.z); d[3] = f2b(v.w);
}

// gather edge_attr rows in dst-sorted order, cast to bf16 (once; step-invariant)
__global__ __launch_bounds__(256)
void gcvt(const float* __restrict__ EA, const int* __restrict__ perm,
          int rows, unsigned short* __restrict__ EB) {
    const int g = blockIdx.x * 256 + threadIdx.x;
    if (g >= rows * 32) return;
    const int r = g >> 5, j = (g & 31) * 4;
    const int e = perm[r];
    const float4 v = *(const float4*)(EA + (size_t)e * DEE + j);
    unsigned short* d = EB + (size_t)r * DEE + j;
    d[0] = f2b(v.x); d[1] = f2b(v.y); d[2] = f2b(v.z); d[3] = f2b(v.w);
}

// wave-per-node gather-reduce: s[v] += sum_p ReLU(EW'[p] + U[v] + b1)
__global__ __launch_bounds__(256)
void aggregate(const unsigned short* __restrict__ EW, const int* __restrict__ off,
               const unsigned short* __restrict__ UV, const float* __restrict__ b1,
               int p0, int p1, float* __restrict__ s) {
    const int v = blockIdx.x * 4 + (threadIdx.x >> 6);
    const int lane = threadIdx.x & 63;
    int lo = off[v], hi = off[v + 1];
    if (lo < p0) lo = p0;
    if (hi > p1) hi = p1;
    if (lo >= hi) return;
    const int q = lane * 4;
    const ushort4 u4 = *(const ushort4*)(UV + (size_t)v * 512 + q);
    const float4 bb = *(const float4*)(b1 + q);
    const float base0 = b2f(u4.x) + bb.x, base1 = b2f(u4.y) + bb.y,
                base2 = b2f(u4.z) + bb.z, base3 = b2f(u4.w) + bb.w;
    float a0 = 0.f, a1 = 0.f, a2 = 0.f, a3 = 0.f;
    const unsigned short* ep = EW + (size_t)(lo - p0) * 256 + q;
    int n = hi - lo;
    while (n >= 4) {
        const ushort4 e0 = *(const ushort4*)(ep);
        const ushort4 e1 = *(const ushort4*)(ep + 256);
        const ushort4 e2 = *(const ushort4*)(ep + 512);
        const ushort4 e3 = *(const ushort4*)(ep + 768);
        ep += 1024; n -= 4;
        a0 += fmaxf(b2f(e0.x) + base0, 0.f); a1 += fmaxf(b2f(e0.y) + base1, 0.f);
        a2 += fmaxf(b2f(e0.z) + base2, 0.f); a3 += fmaxf(b2f(e0.w) + base3, 0.f);
        a0 += fmaxf(b2f(e1.x) + base0, 0.f); a1 += fmaxf(b2f(e1.y) + base1, 0.f);
        a2 += fmaxf(b2f(e1.z) + base2, 0.f); a3 += fmaxf(b2f(e1.w) + base3, 0.f);
        a0 += fmaxf(b2f(e2.x) + base0, 0.f); a1 += fmaxf(b2f(e2.y) + base1, 0.f);
        a2 += fmaxf(b2f(e2.z) + base2, 0.f); a3 += fmaxf(b2f(e2.w) + base3, 0.f);
        a0 += fmaxf(b2f(e3.x) + base0, 0.f); a1 += fmaxf(b2f(e3.y) + base1, 0.f);
        a2 += fmaxf(b2f(e3.z) + base2, 0.f); a3 += fmaxf(b2f(e3.w) + base3, 0.f);
    }
    while (n > 0) {
        const ushort4 e0 = *(const ushort4*)ep;
        ep += 256; --n;
        a0 += fmaxf(b2f(e0.x) + base0, 0.f); a1 += fmaxf(b2f(e0.y) + base1, 0.f);
        a2 += fmaxf(b2f(e0.z) + base2, 0.f); a3 += fmaxf(b2f(e0.w) + base3, 0.f);
    }
    float* sp = s + (size_t)v * 256 + q;
    float4 sv = *(float4*)sp;
    sv.x += a0; sv.y += a1; sv.z += a2; sv.w += a3;
    *(float4*)sp = sv;
}

__global__ __launch_bounds__(256)
void count_deg(const int* __restrict__ dst, int* __restrict__ deg) {
    const int e = blockIdx.x * 256 + threadIdx.x;
    if (e < NED) atomicAdd(&deg[dst[e]], 1);
}

// 1024-thread shuffle-based exclusive scan deg -> off, cursor
__global__ __launch_bounds__(1024)
void scan_offsets(const int* __restrict__ deg, int* __restrict__ off,
                  int* __restrict__ cursor) {
    __shared__ int wpre[16];
    __shared__ int stot;
    const int t = threadIdx.x, wid = t >> 6, lane = t & 63;
    int carry = 0;
    for (int base = 0; base < 20480; base += 1024) {
        const int idx = base + t;
        const int val = (idx < NND) ? deg[idx] : 0;
        int x = val;
        #pragma unroll
        for (int d = 1; d < 64; d <<= 1) {
            const int y = __shfl_up(x, d, 64);
            if (lane >= d) x += y;
        }
        if (lane == 63) wpre[wid] = x;
        __syncthreads();
        if (wid == 0 && lane < 16) {
            const int w = wpre[lane];
            int xx = w;
            #pragma unroll
            for (int d = 1; d < 16; d <<= 1) {
                const int y = __shfl_up(xx, d, 16);
                if (lane >= d) xx += y;
            }
            wpre[lane] = xx - w;
            if (lane == 15) stot = xx;
        }
        __syncthreads();
        const int ex = carry + wpre[wid] + x - val;
        if (idx < NND) { off[idx] = ex; cursor[idx] = ex; }
        carry += stot;
        __syncthreads();
    }
    if (t == 0) off[NND] = carry;
}

__global__ __launch_bounds__(256)
void scatter_edges(const int* __restrict__ dst, const int* __restrict__ src,
                   int* __restrict__ cursor, int* __restrict__ perm,
                   int* __restrict__ srcS) {
    const int e = blockIdx.x * 256 + threadIdx.x;
    if (e < NED) {
        const int d = dst[e];
        const int p = atomicAdd(&cursor[d], 1);
        perm[p] = e;
        srcS[p] = src[e];
    }
}

__global__ __launch_bounds__(256)
void cvt_a(const float* __restrict__ a, const int* __restrict__ deg,
           const float* __restrict__ b2, unsigned short* __restrict__ hab) {
    const int t = blockIdx.x * 256 + threadIdx.x;
    const int v = t >> 6, q = (t & 63) * 4;
    const float dv = (float)deg[v];
    const float4 b4 = *(const float4*)(b2 + q);
    const float4 av = *(const float4*)(a + (size_t)v * DD + q);
    unsigned short* d = hab + (size_t)v * 512 + 256 + q;
    d[0] = f2b(av.x + dv * b4.x); d[1] = f2b(av.y + dv * b4.y);
    d[2] = f2b(av.z + dv * b4.z); d[3] = f2b(av.w + dv * b4.w);
}

__device__ __forceinline__ float sigf(float x) { return 1.0f / (1.0f + expf(-x)); }

__global__ __launch_bounds__(256)
void lstm_update(const unsigned short* __restrict__ gates, float* __restrict__ c,
                 unsigned short* __restrict__ hab) {
    const int t = blockIdx.x * 256 + threadIdx.x;
    const int v = t >> 6, q = (t & 63) * 4;
    const unsigned short* gp = gates + (size_t)v * 1024;
    const ushort4 i4 = *(const ushort4*)(gp + q);
    const ushort4 f4 = *(const ushort4*)(gp + 256 + q);
    const ushort4 g4 = *(const ushort4*)(gp + 512 + q);
    const ushort4 o4 = *(const ushort4*)(gp + 768 + q);
    float4 cc = *(float4*)(c + (size_t)v * DD + q);
    float nc[4], nh[4];
    const float ig[4] = {b2f(i4.x), b2f(i4.y), b2f(i4.z), b2f(i4.w)};
    const float fg[4] = {b2f(f4.x), b2f(f4.y), b2f(f4.z), b2f(f4.w)};
    const float gg[4] = {b2f(g4.x), b2f(g4.y), b2f(g4.z), b2f(g4.w)};
    const float og[4] = {b2f(o4.x), b2f(o4.y), b2f(o4.z), b2f(o4.w)};
    const float co[4] = {cc.x, cc.y, cc.z, cc.w};
    #pragma unroll
    for (int j = 0; j < 4; ++j) {
        nc[j] = sigf(fg[j]) * co[j] + sigf(ig[j]) * tanhf(gg[j]);
        nh[j] = sigf(og[j]) * tanhf(nc[j]);
    }
    cc.x = nc[0]; cc.y = nc[1]; cc.z = nc[2]; cc.w = nc[3];
    *(float4*)(c + (size_t)v * DD + q) = cc;
    unsigned short* d = hab + (size_t)v * 512 + q;
    d[0] = f2b(nh[0]); d[1] = f2b(nh[1]); d[2] = f2b(nh[2]); d[3] = f2b(nh[3]);
}

__global__ __launch_bounds__(256)
void prep_bias(const float* __restrict__ b_ih, const float* __restrict__ b_hh,
               const float* __restrict__ gm_b, const float* __restrict__ fm_b,
               float* __restrict__ bsum, float* __restrict__ gfb) {
    const int t = blockIdx.x * 256 + threadIdx.x;
    if (t < 2048) bsum[t] = b_ih[t] + b_hh[t];
    else if (t < 2304) gfb[t - 2048] = gm_b[t - 2048];
    else if (t < 2560) gfb[t - 2048] = fm_b[t - 2304];
}

__global__ __launch_bounds__(256)
void readout_reduce(const float* __restrict__ RO, float* __restrict__ out) {
    const int g = threadIdx.x;
    const int v0 = blockIdx.x * 128;
    float acc = 0.f;
    const int vend = (v0 + 128 < NND) ? v0 + 128 : NND;
    for (int v = v0; v < vend; ++v) {
        acc += sigf(RO[(size_t)v * 512 + g]) * RO[(size_t)v * 512 + 256 + g];
    }
    atomicAdd(&out[g], acc);
}

extern "C" void kernel_launch(void* const* d_in, const int* in_sizes, int n_in,
                              void* d_out, int out_size, void* d_ws, size_t ws_size,
                              hipStream_t stream) {
    const float* x         = (const float*)d_in[0];
    const float* edge_attr = (const float*)d_in[1];
    const int*   eidx      = (const int*)d_in[2];
    const float* fe1_W     = (const float*)d_in[3];
    const float* fe1_b     = (const float*)d_in[4];
    const float* fe2_W     = (const float*)d_in[5];
    const float* fe2_b     = (const float*)d_in[6];
    const float* W_ih      = (const float*)d_in[7];
    const float* W_hh      = (const float*)d_in[8];
    const float* b_ih      = (const float*)d_in[9];
    const float* b_hh      = (const float*)d_in[10];
    const float* gm_W      = (const float*)d_in[11];
    const float* gm_b      = (const float*)d_in[12];
    const float* fm_W      = (const float*)d_in[13];
    const float* fm_b      = (const float*)d_in[14];
    float* out = (float*)d_out;

    const int* src = eidx;
    const int* dst = eidx + NED;

    float* ws = (float*)d_ws;
    unsigned short* UVb    = (unsigned short*)ws;
    float*          s      = ws + 5120000L;
    float*          a      = ws + 10240000L;
    unsigned short* gatesb = (unsigned short*)ws;
    float*          RO     = ws;
    float*          c      = ws + 15360000L;
    unsigned short* hab    = (unsigned short*)(ws + 20480000L);
    unsigned short* sb     = (unsigned short*)(ws + 25600000L);
    unsigned short* wb     = (unsigned short*)(ws + 28160000L);
    float*          bias_f = ws + 29060000L;
    int*            ib     = (int*)(ws + 29070000L);
    int* deg    = ib;
    int* off    = ib + 20000;
    int* perm   = ib + 40001;
    int* srcS   = ib + 360001;
    int* cursor = ib + 680001;

    unsigned short* EABs = (unsigned short*)(ws + 29800000L);   // NED x 128 bf16
    const long EW0 = 29800000L + (long)NED * 64;                // 50.28M floats
    unsigned short* EWb = (unsigned short*)(ws + EW0);

    const long total_f = (long)(ws_size / sizeof(float));
    long cap = ((total_f - EW0) / 128) & ~127L;
    if (cap > 65536) cap = 65536;       // ~33.5 MB chunk: stays L2/L3-resident
    if (cap < 2560) cap = 2560;

    // weight table offsets (bf16 elements)
    const long WUV = 0;        // [i]: 512x256  (+i*131072)
    const long WEB = 262144;   // [i]: 256x128  (+i*32768)
    const long WF2 = 327680;   // [i]: 256x256  (+i*65536)
    const long WG  = 458752;   // [i]: 1024x512 (+i*524288)
    const long WGM = 1507328;  // 512x256

    // ---- one-time setup ----------------------------------------------------
    hipMemsetAsync(c, 0, (size_t)NND * DD * 4, stream);
    hipMemsetAsync(deg, 0, (size_t)NND * 4, stream);
    count_deg<<<(NED + 255) / 256, 256, 0, stream>>>(dst, deg);
    scan_offsets<<<1, 1024, 0, stream>>>(deg, off, cursor);
    scatter_edges<<<(NED + 255) / 256, 256, 0, stream>>>(dst, src, cursor, perm, srcS);
    prep_bias<<<10, 256, 0, stream>>>(b_ih, b_hh, gm_b, fm_b, bias_f, bias_f + 2048);
    cast_blk<<<5000, 256, 0, stream>>>(x, 256, 0, NND, 256, hab, 512, 0, 0);
    gcvt<<<40000, 256, 0, stream>>>(edge_attr, perm, NED, EABs);
    for (int i = 0; i < 2; ++i) {
        const float* W1 = fe1_W + (size_t)i * 256 * 640;
        cast_blk<<<64, 256, 0, stream>>>(W1, 640, 0,   256, 256, wb + WUV + i * 131072, 256, 0, 0);
        cast_blk<<<64, 256, 0, stream>>>(W1, 640, 256, 256, 256, wb + WUV + i * 131072, 256, 256, 0);
        cast_blk<<<32, 256, 0, stream>>>(W1, 640, 512, 256, 128, wb + WEB + i * 32768, 128, 0, 0);
        cast_blk<<<64, 256, 0, stream>>>(fe2_W + (size_t)i * 65536, 256, 0, 256, 256,
                                         wb + WF2 + i * 65536, 256, 0, 0);
        cast_blk<<<256, 256, 0, stream>>>(W_ih + (size_t)i * 262144, 256, 0, 1024, 256,
                                          wb + WG + i * 524288, 512, 0, 0);
        cast_blk<<<256, 256, 0, stream>>>(W_hh + (size_t)i * 262144, 256, 0, 1024, 256,
                                          wb + WG + i * 524288, 512, 0, 256);
    }
    cast_blk<<<64, 256, 0, stream>>>(gm_W, 256, 0, 256, 256, wb + WGM, 256, 0, 0);
    cast_blk<<<64, 256, 0, stream>>>(fm_W, 256, 0, 256, 256, wb + WGM, 256, 256, 0);

    const dim3 gUV(157, 4), gF2(157, 2), gGT(157, 8), gRO(157, 4);

    for (int i = 0; i < 2; ++i) {
        mgemm<true, false, false><<<gUV, 256, 0, stream>>>(hab, 512, wb + WUV + i * 131072,
            nullptr, UVb, NND, 512, 256, nullptr, nullptr, 0);
        hipMemsetAsync(s, 0, (size_t)NND * DD * 4, stream);
        for (long p0 = 0; p0 < NED; p0 += cap) {
            const long p1 = (p0 + cap < NED) ? p0 + cap : NED;
            const int rows = (int)(p1 - p0);
            mgemm<true, false, true><<<dim3((rows + 127) / 128, 2), 256, 0, stream>>>(
                EABs + (size_t)p0 * DEE, DEE, wb + WEB + i * 32768, nullptr, EWb,
                rows, 256, DEE, srcS, UVb, (int)p0);
            aggregate<<<5000, 256, 0, stream>>>(EWb, off, UVb,
                fe1_b + (size_t)i * 256, (int)p0, (int)p1, s);
        }
        cast_blk<<<5000, 256, 0, stream>>>(s, 256, 0, NND, 256, sb, 256, 0, 0);
        mgemm<false, false, false><<<gF2, 256, 0, stream>>>(sb, 256, wb + WF2 + i * 65536,
            nullptr, a, NND, 256, 256, nullptr, nullptr, 0);
        cvt_a<<<5000, 256, 0, stream>>>(a, deg, fe2_b + (size_t)i * 256, hab);
        mgemm<true, true, false><<<gGT, 256, 0, stream>>>(hab, 512, wb + WG + i * 524288,
            bias_f + (size_t)i * 1024, gatesb, NND, 1024, 512, nullptr, nullptr, 0);
        lstm_update<<<5000, 256, 0, stream>>>(gatesb, c, hab);
    }

    mgemm<false, true, false><<<gRO, 256, 0, stream>>>(hab, 512, wb + WGM,
        bias_f + 2048, RO, NND, 512, 256, nullptr, nullptr, 0);
    hipMemsetAsync(out, 0, 256 * 4, stream);
    readout_reduce<<<157, 256, 0, stream>>>(RO, out);
}

// Round 6
// 813.634 us; speedup vs baseline: 4.0369x; 1.0982x over previous
//
#include <hip/hip_runtime.h>
#include <hip/hip_bf16.h>
#include <math.h>

#define NND 20000
#define NED 320000
#define DD  256
#define DEE 128

typedef __attribute__((ext_vector_type(8))) short bf16x8;
typedef __attribute__((ext_vector_type(4))) float f32x4;

__device__ __forceinline__ float b2f(unsigned short u) {
    union { float f; unsigned int i; } x; x.i = ((unsigned int)u) << 16; return x.f;
}
__device__ __forceinline__ unsigned short f2b(float f) {
    union { float f; unsigned int i; } x; x.f = f;
    unsigned int r = x.i + 0x7fffu + ((x.i >> 16) & 1u);
    return (unsigned short)(r >> 16);
}
__device__ __forceinline__ float sigf(float x) { return 1.0f / (1.0f + expf(-x)); }

__device__ __forceinline__ void gload_lds16(const void* g, void* l) {
    __builtin_amdgcn_global_load_lds((const __attribute__((address_space(1))) void*)g,
                                     (__attribute__((address_space(3))) void*)l, 16, 0, 0);
}

// ---------------------------------------------------------------------------
// bf16 MFMA GEMM, 128x128 tile, BK=32, 256 threads (4 waves 2x2), 16x16x32.
// EPI 0: f32 out [row*N+col] + bias[col]      (readout)
// EPI 1: bf16 out [row*N+col], no bias        (UV)
// EPI 2: bf16 out hab[row*512+256+col] = acc + deg[row]*bias[col]  (fe2+a)
// ---------------------------------------------------------------------------
template<int EPI>
__global__ __launch_bounds__(256)
void mgemm(const unsigned short* __restrict__ A, int lda,
           const unsigned short* __restrict__ W,
           const float* __restrict__ bias,
           void* __restrict__ Cv, int M, int N, int K,
           const int* __restrict__ deg) {
    __shared__ unsigned short As[128 * 32];
    __shared__ unsigned short Bs[128 * 32];
    const int m0 = blockIdx.x * 128;
    const int n0 = blockIdx.y * 128;
    const int tid = threadIdx.x;
    const int wid = tid >> 6, lane = tid & 63;
    const int wr = wid >> 1, wc = wid & 1;
    const int sr = tid >> 2;
    const int sc = (tid & 3) * 8;

    int ra0 = m0 + sr;      if (ra0 >= M) ra0 = M - 1;
    int ra1 = m0 + 64 + sr; if (ra1 >= M) ra1 = M - 1;
    const int rb0 = n0 + sr, rb1 = n0 + 64 + sr;

    char* lA = (char*)As + wid * 1024;
    char* lB = (char*)Bs + wid * 1024;

    f32x4 acc[4][4] = {};
    for (int k0 = 0; k0 < K; k0 += 32) {
        __syncthreads();
        gload_lds16(A + (size_t)ra0 * lda + k0 + sc, lA);
        gload_lds16(A + (size_t)ra1 * lda + k0 + sc, lA + 4096);
        gload_lds16(W + (size_t)rb0 * K + k0 + sc, lB);
        gload_lds16(W + (size_t)rb1 * K + k0 + sc, lB + 4096);
        __syncthreads();

        bf16x8 af[4], bfr[4];
        const int ar = wr * 64 + (lane & 15);
        const int br = wc * 64 + (lane & 15);
        const int ke = (lane >> 4) * 8;
        #pragma unroll
        for (int m = 0; m < 4; ++m) af[m] = *(const bf16x8*)&As[(ar + m * 16) * 32 + ke];
        #pragma unroll
        for (int n = 0; n < 4; ++n) bfr[n] = *(const bf16x8*)&Bs[(br + n * 16) * 32 + ke];
        #pragma unroll
        for (int m = 0; m < 4; ++m)
            #pragma unroll
            for (int n = 0; n < 4; ++n)
                acc[m][n] = __builtin_amdgcn_mfma_f32_16x16x32_bf16(af[m], bfr[n], acc[m][n], 0, 0, 0);
    }

    const int r0 = m0 + wr * 64 + (lane >> 4) * 4;
    const int c0 = n0 + wc * 64 + (lane & 15);
    #pragma unroll
    for (int n = 0; n < 4; ++n) {
        const int col = c0 + n * 16;
        const float bv = (EPI != 1) ? bias[col] : 0.f;
        #pragma unroll
        for (int m = 0; m < 4; ++m) {
            #pragma unroll
            for (int j = 0; j < 4; ++j) {
                const int row = r0 + m * 16 + j;
                if (row < M) {
                    if (EPI == 0) {
                        ((float*)Cv)[(size_t)row * N + col] = acc[m][n][j] + bv;
                    } else if (EPI == 1) {
                        ((unsigned short*)Cv)[(size_t)row * N + col] = f2b(acc[m][n][j]);
                    } else {
                        const float v = acc[m][n][j] + (float)deg[row] * bv;
                        ((unsigned short*)Cv)[(size_t)row * 512 + 256 + col] = f2b(v);
                    }
                }
            }
        }
    }
}

// ---------------------------------------------------------------------------
// Fused edge message + segment reduce.
// Tile: 128 sorted edges x 128 cols (grid.y=2 halves of 256).
//   acc = EAB[e0..e0+128) @ We^T; val = ReLU(acc + U[dst]+V[src]+b1) -> LDS T
//   segment-sum T rows by dst (sorted); interior segs: plain store to s,
//   first/last segs: atomicAdd (s pre-zeroed).
// ---------------------------------------------------------------------------
__global__ __launch_bounds__(256)
void edge_fused(const unsigned short* __restrict__ EAB,
                const unsigned short* __restrict__ W,
                const float* __restrict__ b1,
                const unsigned short* __restrict__ UV,
                const int* __restrict__ srcS, const int* __restrict__ dstS,
                float* __restrict__ s) {
    __shared__ unsigned short As[128 * 32];
    __shared__ unsigned short Bs[128 * 32];
    __shared__ unsigned short T[128][136];
    __shared__ int dloc[128];
    __shared__ int segs[130];
    __shared__ unsigned long long smask[2];
    __shared__ int nseg;

    const int e0 = blockIdx.x * 128;
    const int n0 = blockIdx.y * 128;
    const int tid = threadIdx.x;
    const int wid = tid >> 6, lane = tid & 63;
    const int wr = wid >> 1, wc = wid & 1;
    const int sr = tid >> 2;
    const int sc = (tid & 3) * 8;

    const int ra0 = e0 + sr, ra1 = e0 + 64 + sr;
    const int rb0 = n0 + sr, rb1 = n0 + 64 + sr;
    char* lA = (char*)As + wid * 1024;
    char* lB = (char*)Bs + wid * 1024;

    f32x4 acc[4][4] = {};
    for (int k0 = 0; k0 < DEE; k0 += 32) {
        __syncthreads();
        gload_lds16(EAB + (size_t)ra0 * DEE + k0 + sc, lA);
        gload_lds16(EAB + (size_t)ra1 * DEE + k0 + sc, lA + 4096);
        gload_lds16(W + (size_t)rb0 * DEE + k0 + sc, lB);
        gload_lds16(W + (size_t)rb1 * DEE + k0 + sc, lB + 4096);
        __syncthreads();

        bf16x8 af[4], bfr[4];
        const int ar = wr * 64 + (lane & 15);
        const int br = wc * 64 + (lane & 15);
        const int ke = (lane >> 4) * 8;
        #pragma unroll
        for (int m = 0; m < 4; ++m) af[m] = *(const bf16x8*)&As[(ar + m * 16) * 32 + ke];
        #pragma unroll
        for (int n = 0; n < 4; ++n) bfr[n] = *(const bf16x8*)&Bs[(br + n * 16) * 32 + ke];
        #pragma unroll
        for (int m = 0; m < 4; ++m)
            #pragma unroll
            for (int n = 0; n < 4; ++n)
                acc[m][n] = __builtin_amdgcn_mfma_f32_16x16x32_bf16(af[m], bfr[n], acc[m][n], 0, 0, 0);
    }

    // epilogue -> T (bf16), adding U[dst], V[src], b1
    const int lr0 = wr * 64 + (lane >> 4) * 4;
    const int lc0 = wc * 64 + (lane & 15);
    float bbv[4];
    #pragma unroll
    for (int n = 0; n < 4; ++n) bbv[n] = b1[n0 + lc0 + n * 16];
    #pragma unroll
    for (int m = 0; m < 4; ++m) {
        #pragma unroll
        for (int j = 0; j < 4; ++j) {
            const int r = lr0 + m * 16 + j;
            const int e = e0 + r;
            const int sv = srcS[e];
            const int dv = dstS[e];
            #pragma unroll
            for (int n = 0; n < 4; ++n) {
                const int cl = lc0 + n * 16;
                const int gcol = n0 + cl;
                const float val = acc[m][n][j] + b2f(UV[(size_t)dv * 512 + gcol])
                                + b2f(UV[(size_t)sv * 512 + 256 + gcol]) + bbv[n];
                T[r][cl] = f2b(val > 0.f ? val : 0.f);
            }
        }
    }
    if (tid < 128) dloc[tid] = dstS[e0 + tid];
    __syncthreads();

    if (tid < 128) {
        const int b = (tid == 0) || (dloc[tid] != dloc[tid - 1]);
        const unsigned long long mk = __ballot(b);
        if ((tid & 63) == 0) smask[tid >> 6] = mk;
    }
    __syncthreads();
    if (tid == 0) {
        int k = 0;
        #pragma unroll
        for (int w2 = 0; w2 < 2; ++w2) {
            unsigned long long m = smask[w2];
            while (m) {
                const int b2_ = __ffsll((long long)m) - 1;
                segs[k++] = w2 * 64 + b2_;
                m &= m - 1;
            }
        }
        segs[k] = 128;
        nseg = k;
    }
    __syncthreads();

    if (tid < 128) {
        const int col = tid;
        const int ns = nseg;
        for (int g2 = 0; g2 < ns; ++g2) {
            const int lo = segs[g2], hi = segs[g2 + 1];
            float a2 = 0.f;
            for (int r = lo; r < hi; ++r) a2 += b2f(T[r][col]);
            const int node = dloc[lo];
            float* dp = s + (size_t)node * 256 + n0 + col;
            if (g2 == 0 || g2 == ns - 1) atomicAdd(dp, a2);
            else *dp = a2;
        }
    }
}

// ---------------------------------------------------------------------------
// gates GEMM (K=512, N=1024 gate-interleaved weights) + fused LSTM cell.
// Reads Ain (= current hab [h|a]); writes new h into habOut h-part (no race).
// Weight row r' corresponds to (gate=(r'>>4)&3, dim=((r'>>6)<<4)|(r'&15)).
// Each lane's 4 n-fragments are gates i,f,g,o of one dim.
// ---------------------------------------------------------------------------
__global__ __launch_bounds__(256)
void gemm_lstm(const unsigned short* __restrict__ Ain,
               const unsigned short* __restrict__ W,
               const float* __restrict__ pb,
               float* __restrict__ c, unsigned short* __restrict__ habOut, int M) {
    __shared__ unsigned short As[128 * 32];
    __shared__ unsigned short Bs[128 * 32];
    const int m0 = blockIdx.x * 128;
    const int n0 = blockIdx.y * 128;
    const int tid = threadIdx.x;
    const int wid = tid >> 6, lane = tid & 63;
    const int wr = wid >> 1, wc = wid & 1;
    const int sr = tid >> 2;
    const int sc = (tid & 3) * 8;

    int ra0 = m0 + sr;      if (ra0 >= M) ra0 = M - 1;
    int ra1 = m0 + 64 + sr; if (ra1 >= M) ra1 = M - 1;
    const int rb0 = n0 + sr, rb1 = n0 + 64 + sr;
    char* lA = (char*)As + wid * 1024;
    char* lB = (char*)Bs + wid * 1024;

    f32x4 acc[4][4] = {};
    for (int k0 = 0; k0 < 512; k0 += 32) {
        __syncthreads();
        gload_lds16(Ain + (size_t)ra0 * 512 + k0 + sc, lA);
        gload_lds16(Ain + (size_t)ra1 * 512 + k0 + sc, lA + 4096);
        gload_lds16(W + (size_t)rb0 * 512 + k0 + sc, lB);
        gload_lds16(W + (size_t)rb1 * 512 + k0 + sc, lB + 4096);
        __syncthreads();

        bf16x8 af[4], bfr[4];
        const int ar = wr * 64 + (lane & 15);
        const int br = wc * 64 + (lane & 15);
        const int ke = (lane >> 4) * 8;
        #pragma unroll
        for (int m = 0; m < 4; ++m) af[m] = *(const bf16x8*)&As[(ar + m * 16) * 32 + ke];
        #pragma unroll
        for (int n = 0; n < 4; ++n) bfr[n] = *(const bf16x8*)&Bs[(br + n * 16) * 32 + ke];
        #pragma unroll
        for (int m = 0; m < 4; ++m)
            #pragma unroll
            for (int n = 0; n < 4; ++n)
                acc[m][n] = __builtin_amdgcn_mfma_f32_16x16x32_bf16(af[m], bfr[n], acc[m][n], 0, 0, 0);
    }

    const int r0 = m0 + wr * 64 + (lane >> 4) * 4;
    const int c0 = n0 + wc * 64 + (lane & 15);
    const int dim = ((c0 >> 6) << 4) | (lane & 15);
    float pbv[4];
    #pragma unroll
    for (int n = 0; n < 4; ++n) pbv[n] = pb[c0 + n * 16];
    #pragma unroll
    for (int m = 0; m < 4; ++m) {
        #pragma unroll
        for (int j = 0; j < 4; ++j) {
            const int v = r0 + m * 16 + j;
            if (v < M) {
                const float gi = acc[m][0][j] + pbv[0];
                const float gf = acc[m][1][j] + pbv[1];
                const float gg = acc[m][2][j] + pbv[2];
                const float go = acc[m][3][j] + pbv[3];
                const float cold = c[(size_t)v * 256 + dim];
                const float nc = sigf(gf) * cold + sigf(gi) * tanhf(gg);
                const float nh = sigf(go) * tanhf(nc);
                c[(size_t)v * 256 + dim] = nc;
                habOut[(size_t)v * 512 + dim] = f2b(nh);
            }
        }
    }
}

__global__ __launch_bounds__(256)
void cast_blk(const float* __restrict__ src, int lds_, int col0,
              int rows, int cols, unsigned short* __restrict__ dst,
              int ldd, int dr, int dc) {
    const long g = ((long)blockIdx.x * 256 + threadIdx.x) * 4;
    if (g >= (long)rows * cols) return;
    const int r = (int)(g / cols), cc = (int)(g % cols);
    const float4 v = *(const float4*)(src + (size_t)r * lds_ + col0 + cc);
    unsigned short* d = dst + (size_t)(dr + r) * ldd + dc + cc;
    d[0] = f2b(v.x); d[1] = f2b(v.y); d[2] = f2b(v.z); d[3] = f2b(v.w);
}

// all weights -> bf16 table (incl. gate-interleaved WG permutation)
__global__ __launch_bounds__(256)
void cast_weights(const float* __restrict__ fe1, const float* __restrict__ fe2,
                  const float* __restrict__ wih, const float* __restrict__ whh,
                  const float* __restrict__ gmw, const float* __restrict__ fmw,
                  unsigned short* __restrict__ wb) {
    const long o = ((long)blockIdx.x * 256 + threadIdx.x) * 4;
    if (o >= 1638400L) return;
    const float* srcp;
    if (o < 262144L) {                       // WUV: [i][512][256]
        const int i = (int)(o >> 17); const int w = (int)(o & 131071);
        const int r = w >> 8, col = w & 255;
        srcp = fe1 + (size_t)i * 163840 + (r < 256 ? (size_t)r * 640 + col
                                                   : (size_t)(r - 256) * 640 + 256 + col);
    } else if (o < 327680L) {                // WEB: [i][256][128]
        const long w = o - 262144L;
        const int i = (int)(w >> 15); const int ww = (int)(w & 32767);
        srcp = fe1 + (size_t)i * 163840 + (size_t)(ww >> 7) * 640 + 512 + (ww & 127);
    } else if (o < 458752L) {                // WF2: [i][256][256]
        const long w = o - 327680L;
        const int i = (int)(w >> 16); const int ww = (int)(w & 65535);
        srcp = fe2 + (size_t)i * 65536 + ww;
    } else if (o < 1507328L) {               // WG: [i][1024'][512], gate-interleaved
        const long w = o - 458752L;
        const int i = (int)(w >> 19); const int ww = (int)(w & 524287);
        const int rp = ww >> 9, k = ww & 511;
        const int gate = (rp >> 4) & 3;
        const int dim = ((rp >> 6) << 4) | (rp & 15);
        const int orig = gate * 256 + dim;
        srcp = (k < 256) ? wih + (size_t)i * 262144 + (size_t)orig * 256 + k
                         : whh + (size_t)i * 262144 + (size_t)orig * 256 + (k - 256);
    } else {                                 // WGM: [512][256]
        const long w = o - 1507328L;
        const int r = (int)(w >> 8), col = (int)(w & 255);
        srcp = (r < 256) ? gmw + (size_t)r * 256 + col
                         : fmw + (size_t)(r - 256) * 256 + col;
    }
    const float4 v = *(const float4*)srcp;
    wb[o] = f2b(v.x); wb[o + 1] = f2b(v.y); wb[o + 2] = f2b(v.z); wb[o + 3] = f2b(v.w);
}

__global__ __launch_bounds__(256)
void gcvt(const float* __restrict__ EA, const int* __restrict__ perm,
          unsigned short* __restrict__ EB) {
    const int g = blockIdx.x * 256 + threadIdx.x;
    if (g >= NED * 32) return;
    const int r = g >> 5, j = (g & 31) * 4;
    const int e = perm[r];
    const float4 v = *(const float4*)(EA + (size_t)e * DEE + j);
    unsigned short* d = EB + (size_t)r * DEE + j;
    d[0] = f2b(v.x); d[1] = f2b(v.y); d[2] = f2b(v.z); d[3] = f2b(v.w);
}

__global__ __launch_bounds__(256)
void count_deg(const int* __restrict__ dst, int* __restrict__ deg) {
    const int e = blockIdx.x * 256 + threadIdx.x;
    if (e < NED) atomicAdd(&deg[dst[e]], 1);
}

__global__ __launch_bounds__(1024)
void scan_offsets(const int* __restrict__ deg, int* __restrict__ off,
                  int* __restrict__ cursor) {
    __shared__ int wpre[16];
    __shared__ int stot;
    const int t = threadIdx.x, wid = t >> 6, lane = t & 63;
    int carry = 0;
    for (int base = 0; base < 20480; base += 1024) {
        const int idx = base + t;
        const int val = (idx < NND) ? deg[idx] : 0;
        int x = val;
        #pragma unroll
        for (int d = 1; d < 64; d <<= 1) {
            const int y = __shfl_up(x, d, 64);
            if (lane >= d) x += y;
        }
        if (lane == 63) wpre[wid] = x;
        __syncthreads();
        if (wid == 0 && lane < 16) {
            const int w = wpre[lane];
            int xx = w;
            #pragma unroll
            for (int d = 1; d < 16; d <<= 1) {
                const int y = __shfl_up(xx, d, 16);
                if (lane >= d) xx += y;
            }
            wpre[lane] = xx - w;
            if (lane == 15) stot = xx;
        }
        __syncthreads();
        const int ex = carry + wpre[wid] + x - val;
        if (idx < NND) { off[idx] = ex; cursor[idx] = ex; }
        carry += stot;
        __syncthreads();
    }
    if (t == 0) off[NND] = carry;
}

__global__ __launch_bounds__(256)
void scatter_edges(const int* __restrict__ dst, const int* __restrict__ src,
                   int* __restrict__ cursor, int* __restrict__ perm,
                   int* __restrict__ srcS, int* __restrict__ dstS) {
    const int e = blockIdx.x * 256 + threadIdx.x;
    if (e < NED) {
        const int d = dst[e];
        const int p = atomicAdd(&cursor[d], 1);
        perm[p] = e;
        srcS[p] = src[e];
        dstS[p] = d;
    }
}

// pb (gate-interleaved b_ih+b_hh) and gfb (gm_b|fm_b)
__global__ __launch_bounds__(256)
void prep_bias(const float* __restrict__ b_ih, const float* __restrict__ b_hh,
               const float* __restrict__ gm_b, const float* __restrict__ fm_b,
               float* __restrict__ pb, float* __restrict__ gfb) {
    const int t = blockIdx.x * 256 + threadIdx.x;
    if (t < 2048) {
        const int i = t >> 10, cth = t & 1023;
        const int gate = (cth >> 4) & 3;
        const int dim = ((cth >> 6) << 4) | (cth & 15);
        const int orig = gate * 256 + dim;
        pb[t] = b_ih[i * 1024 + orig] + b_hh[i * 1024 + orig];
    } else if (t < 2304) gfb[t - 2048] = gm_b[t - 2048];
    else if (t < 2560) gfb[t - 2048] = fm_b[t - 2304];
}

__global__ __launch_bounds__(256)
void readout_reduce(const float* __restrict__ RO, float* __restrict__ out) {
    const int g = threadIdx.x;
    const int v0 = blockIdx.x * 128;
    float acc = 0.f;
    const int vend = (v0 + 128 < NND) ? v0 + 128 : NND;
    for (int v = v0; v < vend; ++v) {
        acc += sigf(RO[(size_t)v * 512 + g]) * RO[(size_t)v * 512 + 256 + g];
    }
    atomicAdd(&out[g], acc);
}

extern "C" void kernel_launch(void* const* d_in, const int* in_sizes, int n_in,
                              void* d_out, int out_size, void* d_ws, size_t ws_size,
                              hipStream_t stream) {
    const float* x         = (const float*)d_in[0];
    const float* edge_attr = (const float*)d_in[1];
    const int*   eidx      = (const int*)d_in[2];
    const float* fe1_W     = (const float*)d_in[3];
    const float* fe1_b     = (const float*)d_in[4];
    const float* fe2_W     = (const float*)d_in[5];
    const float* fe2_b     = (const float*)d_in[6];
    const float* W_ih      = (const float*)d_in[7];
    const float* W_hh      = (const float*)d_in[8];
    const float* b_ih      = (const float*)d_in[9];
    const float* b_hh      = (const float*)d_in[10];
    const float* gm_W      = (const float*)d_in[11];
    const float* gm_b      = (const float*)d_in[12];
    const float* fm_W      = (const float*)d_in[13];
    const float* fm_b      = (const float*)d_in[14];
    float* out = (float*)d_out;

    const int* src = eidx;
    const int* dst = eidx + NED;

    // ---- workspace layout (float offsets) ----------------------------------
    // [0        ,  5120000) UVb bf16 [20000][512]    (RO f32 [20000][512] late,
    //                                                 spans [0, 10240000))
    // [5120000  , 10240000) s   f32 [20000][256]
    // [10240000 , 12800000) sb  bf16 [20000][256]
    // [12800000 , 17920000) c   f32 [20000][256]
    // [17920000 , 23040000) habA bf16 [20000][512]
    // [23040000 , 23859200) wb  bf16 1638400
    // [23860000 , 23862560) pb/gfb f32
    // [23870000 , 24890002) int block (deg/off/cursor/perm/srcS/dstS)
    // [24900000 , 45380000) EABs bf16 [NED][128]
    // [45380000 , 50500000) habB bf16 [20000][512]   -> 202.0 MB total
    float* ws = (float*)d_ws;
    unsigned short* UVb  = (unsigned short*)ws;
    float*          s    = ws + 5120000L;
    float*          RO   = ws;
    unsigned short* sb   = (unsigned short*)(ws + 10240000L);
    float*          c    = ws + 12800000L;
    unsigned short* habA = (unsigned short*)(ws + 17920000L);
    unsigned short* wb   = (unsigned short*)(ws + 23040000L);
    float*          pb   = ws + 23860000L;
    float*          gfb  = ws + 23862048L;
    int*            ib   = (int*)(ws + 23870000L);
    int* deg    = ib;                 // 20000
    int* off    = ib + 20000;         // 20001
    int* cursor = ib + 40001;         // 20000
    int* perm   = ib + 60002;         // 320000
    int* srcS   = ib + 380002;        // 320000
    int* dstS   = ib + 700002;        // 320000 -> ends 1020002
    unsigned short* EABs = (unsigned short*)(ws + 24900000L);
    unsigned short* habB = (unsigned short*)(ws + 45380000L);

    // weight table offsets (bf16 elements)
    const long WUV = 0;        // [i]: 512x256  (+i*131072)
    const long WEB = 262144;   // [i]: 256x128  (+i*32768)
    const long WF2 = 327680;   // [i]: 256x256  (+i*65536)
    const long WG  = 458752;   // [i]: 1024x512 (+i*524288) gate-interleaved
    const long WGM = 1507328;  // 512x256

    // ---- setup -------------------------------------------------------------
    hipMemsetAsync(c, 0, (size_t)NND * DD * 4, stream);
    hipMemsetAsync(deg, 0, (size_t)NND * 4, stream);
    count_deg<<<(NED + 255) / 256, 256, 0, stream>>>(dst, deg);
    scan_offsets<<<1, 1024, 0, stream>>>(deg, off, cursor);
    scatter_edges<<<(NED + 255) / 256, 256, 0, stream>>>(dst, src, cursor, perm, srcS, dstS);
    prep_bias<<<10, 256, 0, stream>>>(b_ih, b_hh, gm_b, fm_b, pb, gfb);
    cast_blk<<<5000, 256, 0, stream>>>(x, 256, 0, NND, 256, habA, 512, 0, 0);
    gcvt<<<40000, 256, 0, stream>>>(edge_attr, perm, EABs);
    cast_weights<<<1600, 256, 0, stream>>>(fe1_W, fe2_W, W_ih, W_hh, gm_W, fm_W, wb);

    const dim3 gUV(157, 4), gF2(157, 2), gGT(157, 8), gRO(157, 4), gE(2500, 2);

    unsigned short* habC = habA;
    unsigned short* habN = habB;
    for (int i = 0; i < 2; ++i) {
        mgemm<1><<<gUV, 256, 0, stream>>>(habC, 512, wb + WUV + i * 131072,
                                          nullptr, UVb, NND, 512, 256, nullptr);
        hipMemsetAsync(s, 0, (size_t)NND * DD * 4, stream);
        edge_fused<<<gE, 256, 0, stream>>>(EABs, wb + WEB + i * 32768,
                                           fe1_b + (size_t)i * 256, UVb, srcS, dstS, s);
        cast_blk<<<5000, 256, 0, stream>>>(s, 256, 0, NND, 256, sb, 256, 0, 0);
        mgemm<2><<<gF2, 256, 0, stream>>>(sb, 256, wb + WF2 + i * 65536,
                                          fe2_b + (size_t)i * 256, habC, NND, 256, 256, deg);
        gemm_lstm<<<gGT, 256, 0, stream>>>(habC, wb + WG + i * 524288,
                                           pb + (size_t)i * 1024, c, habN, NND);
        unsigned short* tmp = habC; habC = habN; habN = tmp;
    }

    mgemm<0><<<gRO, 256, 0, stream>>>(habC, 512, wb + WGM, gfb, RO, NND, 512, 256, nullptr);
    hipMemsetAsync(out, 0, 256 * 4, stream);
    readout_reduce<<<157, 256, 0, stream>>>(RO, out);
}

// Round 7
// 649.100 us; speedup vs baseline: 5.0601x; 1.2535x over previous
//
#include <hip/hip_runtime.h>
#include <hip/hip_bf16.h>
#include <math.h>

#define NND 20000
#define NED 320000
#define DD  256
#define DEE 128

typedef __attribute__((ext_vector_type(8))) short bf16x8;
typedef __attribute__((ext_vector_type(4))) float f32x4;

__device__ __forceinline__ float b2f(unsigned short u) {
    union { float f; unsigned int i; } x; x.i = ((unsigned int)u) << 16; return x.f;
}
__device__ __forceinline__ unsigned short f2b(float f) {
    union { float f; unsigned int i; } x; x.f = f;
    unsigned int r = x.i + 0x7fffu + ((x.i >> 16) & 1u);
    return (unsigned short)(r >> 16);
}
__device__ __forceinline__ float sigf(float x) { return 1.0f / (1.0f + expf(-x)); }

__device__ __forceinline__ void gload_lds16(const void* g, void* l) {
    __builtin_amdgcn_global_load_lds((const __attribute__((address_space(1))) void*)g,
                                     (__attribute__((address_space(3))) void*)l, 16, 0, 0);
}

// ---------------------------------------------------------------------------
// bf16 MFMA GEMM, 128x128 tile, BK=32, 256 threads (4 waves 2x2), 16x16x32.
// EPI 0: f32 out [row*N+col] + bias[col]      (readout)
// EPI 1: bf16 out [row*N+col], no bias        (UV)
// EPI 2: bf16 out hab[row*512+256+col] = acc + deg[row]*bias[col]  (fe2+a)
// ---------------------------------------------------------------------------
template<int EPI>
__global__ __launch_bounds__(256)
void mgemm(const unsigned short* __restrict__ A, int lda,
           const unsigned short* __restrict__ W,
           const float* __restrict__ bias,
           void* __restrict__ Cv, int M, int N, int K,
           const int* __restrict__ deg) {
    __shared__ unsigned short As[128 * 32];
    __shared__ unsigned short Bs[128 * 32];
    const int m0 = blockIdx.x * 128;
    const int n0 = blockIdx.y * 128;
    const int tid = threadIdx.x;
    const int wid = tid >> 6, lane = tid & 63;
    const int wr = wid >> 1, wc = wid & 1;
    const int sr = tid >> 2;
    const int sc = (tid & 3) * 8;

    int ra0 = m0 + sr;      if (ra0 >= M) ra0 = M - 1;
    int ra1 = m0 + 64 + sr; if (ra1 >= M) ra1 = M - 1;
    const int rb0 = n0 + sr, rb1 = n0 + 64 + sr;

    char* lA = (char*)As + wid * 1024;
    char* lB = (char*)Bs + wid * 1024;

    f32x4 acc[4][4] = {};
    for (int k0 = 0; k0 < K; k0 += 32) {
        __syncthreads();
        gload_lds16(A + (size_t)ra0 * lda + k0 + sc, lA);
        gload_lds16(A + (size_t)ra1 * lda + k0 + sc, lA + 4096);
        gload_lds16(W + (size_t)rb0 * K + k0 + sc, lB);
        gload_lds16(W + (size_t)rb1 * K + k0 + sc, lB + 4096);
        __syncthreads();

        bf16x8 af[4], bfr[4];
        const int ar = wr * 64 + (lane & 15);
        const int br = wc * 64 + (lane & 15);
        const int ke = (lane >> 4) * 8;
        #pragma unroll
        for (int m = 0; m < 4; ++m) af[m] = *(const bf16x8*)&As[(ar + m * 16) * 32 + ke];
        #pragma unroll
        for (int n = 0; n < 4; ++n) bfr[n] = *(const bf16x8*)&Bs[(br + n * 16) * 32 + ke];
        #pragma unroll
        for (int m = 0; m < 4; ++m)
            #pragma unroll
            for (int n = 0; n < 4; ++n)
                acc[m][n] = __builtin_amdgcn_mfma_f32_16x16x32_bf16(af[m], bfr[n], acc[m][n], 0, 0, 0);
    }

    const int r0 = m0 + wr * 64 + (lane >> 4) * 4;
    const int c0 = n0 + wc * 64 + (lane & 15);
    #pragma unroll
    for (int n = 0; n < 4; ++n) {
        const int col = c0 + n * 16;
        const float bv = (EPI != 1) ? bias[col] : 0.f;
        #pragma unroll
        for (int m = 0; m < 4; ++m) {
            #pragma unroll
            for (int j = 0; j < 4; ++j) {
                const int row = r0 + m * 16 + j;
                if (row < M) {
                    if (EPI == 0) {
                        ((float*)Cv)[(size_t)row * N + col] = acc[m][n][j] + bv;
                    } else if (EPI == 1) {
                        ((unsigned short*)Cv)[(size_t)row * N + col] = f2b(acc[m][n][j]);
                    } else {
                        const float v = acc[m][n][j] + (float)deg[row] * bv;
                        ((unsigned short*)Cv)[(size_t)row * 512 + 256 + col] = f2b(v);
                    }
                }
            }
        }
    }
}

// ---------------------------------------------------------------------------
// Fused edge message + segment reduce, coalesced-gather version.
// Tile: 128 sorted edges x 128 cols (grid.y=2 halves of 256).
// Phase 1: acc = EAB @ We^T -> T (raw, bf16). As/Bs alias T (union).
// Phase 2: row-parallel (2 rows x 128 cols): T += U[dst]+V[src]+b1, ReLU.
//          UV reads are coalesced 256B row segments.
// Phase 3: segment-sum by dst (sorted); parity-split over 256 threads;
//          interior segs plain store, boundary segs atomicAdd (s pre-zeroed).
// ---------------------------------------------------------------------------
__global__ __launch_bounds__(256)
void edge_fused(const unsigned short* __restrict__ EAB,
                const unsigned short* __restrict__ W,
                const float* __restrict__ b1,
                const unsigned short* __restrict__ UV,
                const int* __restrict__ srcS, const int* __restrict__ dstS,
                float* __restrict__ s) {
    __shared__ union {
        struct { unsigned short As[4096]; unsigned short Bs[4096]; } g;
        unsigned short T[128][136];
    } sm;
    __shared__ int dloc[128];
    __shared__ int sloc[128];
    __shared__ int segs[130];
    __shared__ unsigned long long smask[2];
    __shared__ int nseg;

    const int e0 = blockIdx.x * 128;
    const int n0 = blockIdx.y * 128;
    const int tid = threadIdx.x;
    const int wid = tid >> 6, lane = tid & 63;
    const int wr = wid >> 1, wc = wid & 1;
    const int sr = tid >> 2;
    const int sc = (tid & 3) * 8;

    const int ra0 = e0 + sr, ra1 = e0 + 64 + sr;
    const int rb0 = n0 + sr, rb1 = n0 + 64 + sr;
    char* lA = (char*)sm.g.As + wid * 1024;
    char* lB = (char*)sm.g.Bs + wid * 1024;

    f32x4 acc[4][4] = {};
    for (int k0 = 0; k0 < DEE; k0 += 32) {
        __syncthreads();
        gload_lds16(EAB + (size_t)ra0 * DEE + k0 + sc, lA);
        gload_lds16(EAB + (size_t)ra1 * DEE + k0 + sc, lA + 4096);
        gload_lds16(W + (size_t)rb0 * DEE + k0 + sc, lB);
        gload_lds16(W + (size_t)rb1 * DEE + k0 + sc, lB + 4096);
        __syncthreads();

        bf16x8 af[4], bfr[4];
        const int ar = wr * 64 + (lane & 15);
        const int br = wc * 64 + (lane & 15);
        const int ke = (lane >> 4) * 8;
        #pragma unroll
        for (int m = 0; m < 4; ++m) af[m] = *(const bf16x8*)&sm.g.As[(ar + m * 16) * 32 + ke];
        #pragma unroll
        for (int n = 0; n < 4; ++n) bfr[n] = *(const bf16x8*)&sm.g.Bs[(br + n * 16) * 32 + ke];
        #pragma unroll
        for (int m = 0; m < 4; ++m)
            #pragma unroll
            for (int n = 0; n < 4; ++n)
                acc[m][n] = __builtin_amdgcn_mfma_f32_16x16x32_bf16(af[m], bfr[n], acc[m][n], 0, 0, 0);
    }
    __syncthreads();   // all As/Bs reads done before T overwrites them

    // Phase 1 epilogue: raw acc -> T (bf16)
    const int lr0 = wr * 64 + (lane >> 4) * 4;
    const int lc0 = wc * 64 + (lane & 15);
    #pragma unroll
    for (int m = 0; m < 4; ++m)
        #pragma unroll
        for (int j = 0; j < 4; ++j)
            #pragma unroll
            for (int n = 0; n < 4; ++n)
                sm.T[lr0 + m * 16 + j][lc0 + n * 16] = f2b(acc[m][n][j]);
    if (tid < 128) dloc[tid] = dstS[e0 + tid];
    else           sloc[tid - 128] = srcS[e0 + tid - 128];
    __syncthreads();

    // Phase 2: += U[dst] + V[src] + b1, ReLU  (coalesced UV row reads)
    {
        const int col = tid & 127;
        const int rh = tid >> 7;
        const float b1v = b1[n0 + col];
        #pragma unroll 4
        for (int rr = 0; rr < 64; ++rr) {
            const int r = rr * 2 + rh;
            const int dv = dloc[r], sv = sloc[r];
            const float u = b2f(UV[(size_t)dv * 512 + n0 + col]);
            const float vv = b2f(UV[(size_t)sv * 512 + 256 + n0 + col]);
            const float val = b2f(sm.T[r][col]) + u + vv + b1v;
            sm.T[r][col] = f2b(val > 0.f ? val : 0.f);
        }
    }

    // segment boundaries from sorted dst
    if (tid < 128) {
        const int b = (tid == 0) || (dloc[tid] != dloc[tid - 1]);
        const unsigned long long mk = __ballot(b);
        if ((tid & 63) == 0) smask[tid >> 6] = mk;
    }
    __syncthreads();
    if (tid == 0) {
        int k = 0;
        #pragma unroll
        for (int w2 = 0; w2 < 2; ++w2) {
            unsigned long long m = smask[w2];
            while (m) {
                const int b2_ = __ffsll((long long)m) - 1;
                segs[k++] = w2 * 64 + b2_;
                m &= m - 1;
            }
        }
        segs[k] = 128;
        nseg = k;
    }
    __syncthreads();

    // Phase 3: parity-parallel segment sums
    {
        const int col = tid & 127;
        const int par = tid >> 7;
        const int ns = nseg;
        for (int g2 = par; g2 < ns; g2 += 2) {
            const int lo = segs[g2], hi = segs[g2 + 1];
            float a2 = 0.f;
            for (int r = lo; r < hi; ++r) a2 += b2f(sm.T[r][col]);
            const int node = dloc[lo];
            float* dp = s + (size_t)node * 256 + n0 + col;
            if (g2 == 0 || g2 == ns - 1) atomicAdd(dp, a2);
            else *dp = a2;
        }
    }
}

// ---------------------------------------------------------------------------
// gates GEMM (K=512, N=1024 gate-interleaved weights) + fused LSTM cell.
// Reads Ain (= current hab [h|a]); writes new h into habOut h-part (no race).
// ---------------------------------------------------------------------------
__global__ __launch_bounds__(256)
void gemm_lstm(const unsigned short* __restrict__ Ain,
               const unsigned short* __restrict__ W,
               const float* __restrict__ pb,
               float* __restrict__ c, unsigned short* __restrict__ habOut, int M) {
    __shared__ unsigned short As[128 * 32];
    __shared__ unsigned short Bs[128 * 32];
    const int m0 = blockIdx.x * 128;
    const int n0 = blockIdx.y * 128;
    const int tid = threadIdx.x;
    const int wid = tid >> 6, lane = tid & 63;
    const int wr = wid >> 1, wc = wid & 1;
    const int sr = tid >> 2;
    const int sc = (tid & 3) * 8;

    int ra0 = m0 + sr;      if (ra0 >= M) ra0 = M - 1;
    int ra1 = m0 + 64 + sr; if (ra1 >= M) ra1 = M - 1;
    const int rb0 = n0 + sr, rb1 = n0 + 64 + sr;
    char* lA = (char*)As + wid * 1024;
    char* lB = (char*)Bs + wid * 1024;

    f32x4 acc[4][4] = {};
    for (int k0 = 0; k0 < 512; k0 += 32) {
        __syncthreads();
        gload_lds16(Ain + (size_t)ra0 * 512 + k0 + sc, lA);
        gload_lds16(Ain + (size_t)ra1 * 512 + k0 + sc, lA + 4096);
        gload_lds16(W + (size_t)rb0 * 512 + k0 + sc, lB);
        gload_lds16(W + (size_t)rb1 * 512 + k0 + sc, lB + 4096);
        __syncthreads();

        bf16x8 af[4], bfr[4];
        const int ar = wr * 64 + (lane & 15);
        const int br = wc * 64 + (lane & 15);
        const int ke = (lane >> 4) * 8;
        #pragma unroll
        for (int m = 0; m < 4; ++m) af[m] = *(const bf16x8*)&As[(ar + m * 16) * 32 + ke];
        #pragma unroll
        for (int n = 0; n < 4; ++n) bfr[n] = *(const bf16x8*)&Bs[(br + n * 16) * 32 + ke];
        #pragma unroll
        for (int m = 0; m < 4; ++m)
            #pragma unroll
            for (int n = 0; n < 4; ++n)
                acc[m][n] = __builtin_amdgcn_mfma_f32_16x16x32_bf16(af[m], bfr[n], acc[m][n], 0, 0, 0);
    }

    const int r0 = m0 + wr * 64 + (lane >> 4) * 4;
    const int c0 = n0 + wc * 64 + (lane & 15);
    const int dim = ((c0 >> 6) << 4) | (lane & 15);
    float pbv[4];
    #pragma unroll
    for (int n = 0; n < 4; ++n) pbv[n] = pb[c0 + n * 16];
    #pragma unroll
    for (int m = 0; m < 4; ++m) {
        #pragma unroll
        for (int j = 0; j < 4; ++j) {
            const int v = r0 + m * 16 + j;
            if (v < M) {
                const float gi = acc[m][0][j] + pbv[0];
                const float gf = acc[m][1][j] + pbv[1];
                const float gg = acc[m][2][j] + pbv[2];
                const float go = acc[m][3][j] + pbv[3];
                const float cold = c[(size_t)v * 256 + dim];
                const float nc = sigf(gf) * cold + sigf(gi) * tanhf(gg);
                const float nh = sigf(go) * tanhf(nc);
                c[(size_t)v * 256 + dim] = nc;
                habOut[(size_t)v * 512 + dim] = f2b(nh);
            }
        }
    }
}

__global__ __launch_bounds__(256)
void cast_blk(const float* __restrict__ src, int lds_, int col0,
              int rows, int cols, unsigned short* __restrict__ dst,
              int ldd, int dr, int dc) {
    const long g = ((long)blockIdx.x * 256 + threadIdx.x) * 4;
    if (g >= (long)rows * cols) return;
    const int r = (int)(g / cols), cc = (int)(g % cols);
    const float4 v = *(const float4*)(src + (size_t)r * lds_ + col0 + cc);
    unsigned short* d = dst + (size_t)(dr + r) * ldd + dc + cc;
    d[0] = f2b(v.x); d[1] = f2b(v.y); d[2] = f2b(v.z); d[3] = f2b(v.w);
}

// all weights -> bf16 table (incl. gate-interleaved WG permutation)
__global__ __launch_bounds__(256)
void cast_weights(const float* __restrict__ fe1, const float* __restrict__ fe2,
                  const float* __restrict__ wih, const float* __restrict__ whh,
                  const float* __restrict__ gmw, const float* __restrict__ fmw,
                  unsigned short* __restrict__ wb) {
    const long o = ((long)blockIdx.x * 256 + threadIdx.x) * 4;
    if (o >= 1638400L) return;
    const float* srcp;
    if (o < 262144L) {                       // WUV: [i][512][256]
        const int i = (int)(o >> 17); const int w = (int)(o & 131071);
        const int r = w >> 8, col = w & 255;
        srcp = fe1 + (size_t)i * 163840 + (r < 256 ? (size_t)r * 640 + col
                                                   : (size_t)(r - 256) * 640 + 256 + col);
    } else if (o < 327680L) {                // WEB: [i][256][128]
        const long w = o - 262144L;
        const int i = (int)(w >> 15); const int ww = (int)(w & 32767);
        srcp = fe1 + (size_t)i * 163840 + (size_t)(ww >> 7) * 640 + 512 + (ww & 127);
    } else if (o < 458752L) {                // WF2: [i][256][256]
        const long w = o - 327680L;
        const int i = (int)(w >> 16); const int ww = (int)(w & 65535);
        srcp = fe2 + (size_t)i * 65536 + ww;
    } else if (o < 1507328L) {               // WG: [i][1024'][512], gate-interleaved
        const long w = o - 458752L;
        const int i = (int)(w >> 19); const int ww = (int)(w & 524287);
        const int rp = ww >> 9, k = ww & 511;
        const int gate = (rp >> 4) & 3;
        const int dim = ((rp >> 6) << 4) | (rp & 15);
        const int orig = gate * 256 + dim;
        srcp = (k < 256) ? wih + (size_t)i * 262144 + (size_t)orig * 256 + k
                         : whh + (size_t)i * 262144 + (size_t)orig * 256 + (k - 256);
    } else {                                 // WGM: [512][256]
        const long w = o - 1507328L;
        const int r = (int)(w >> 8), col = (int)(w & 255);
        srcp = (r < 256) ? gmw + (size_t)r * 256 + col
                         : fmw + (size_t)(r - 256) * 256 + col;
    }
    const float4 v = *(const float4*)srcp;
    wb[o] = f2b(v.x); wb[o + 1] = f2b(v.y); wb[o + 2] = f2b(v.z); wb[o + 3] = f2b(v.w);
}

__global__ __launch_bounds__(256)
void gcvt(const float* __restrict__ EA, const int* __restrict__ perm,
          unsigned short* __restrict__ EB) {
    const int g = blockIdx.x * 256 + threadIdx.x;
    if (g >= NED * 32) return;
    const int r = g >> 5, j = (g & 31) * 4;
    const int e = perm[r];
    const float4 v = *(const float4*)(EA + (size_t)e * DEE + j);
    unsigned short* d = EB + (size_t)r * DEE + j;
    d[0] = f2b(v.x); d[1] = f2b(v.y); d[2] = f2b(v.z); d[3] = f2b(v.w);
}

__global__ __launch_bounds__(256)
void count_deg(const int* __restrict__ dst, int* __restrict__ deg) {
    const int e = blockIdx.x * 256 + threadIdx.x;
    if (e < NED) atomicAdd(&deg[dst[e]], 1);
}

__global__ __launch_bounds__(1024)
void scan_offsets(const int* __restrict__ deg, int* __restrict__ off,
                  int* __restrict__ cursor) {
    __shared__ int wpre[16];
    __shared__ int stot;
    const int t = threadIdx.x, wid = t >> 6, lane = t & 63;
    int carry = 0;
    for (int base = 0; base < 20480; base += 1024) {
        const int idx = base + t;
        const int val = (idx < NND) ? deg[idx] : 0;
        int x = val;
        #pragma unroll
        for (int d = 1; d < 64; d <<= 1) {
            const int y = __shfl_up(x, d, 64);
            if (lane >= d) x += y;
        }
        if (lane == 63) wpre[wid] = x;
        __syncthreads();
        if (wid == 0 && lane < 16) {
            const int w = wpre[lane];
            int xx = w;
            #pragma unroll
            for (int d = 1; d < 16; d <<= 1) {
                const int y = __shfl_up(xx, d, 16);
                if (lane >= d) xx += y;
            }
            wpre[lane] = xx - w;
            if (lane == 15) stot = xx;
        }
        __syncthreads();
        const int ex = carry + wpre[wid] + x - val;
        if (idx < NND) { off[idx] = ex; cursor[idx] = ex; }
        carry += stot;
        __syncthreads();
    }
    if (t == 0) off[NND] = carry;
}

__global__ __launch_bounds__(256)
void scatter_edges(const int* __restrict__ dst, const int* __restrict__ src,
                   int* __restrict__ cursor, int* __restrict__ perm,
                   int* __restrict__ srcS, int* __restrict__ dstS) {
    const int e = blockIdx.x * 256 + threadIdx.x;
    if (e < NED) {
        const int d = dst[e];
        const int p = atomicAdd(&cursor[d], 1);
        perm[p] = e;
        srcS[p] = src[e];
        dstS[p] = d;
    }
}

// pb (gate-interleaved b_ih+b_hh) and gfb (gm_b|fm_b)
__global__ __launch_bounds__(256)
void prep_bias(const float* __restrict__ b_ih, const float* __restrict__ b_hh,
               const float* __restrict__ gm_b, const float* __restrict__ fm_b,
               float* __restrict__ pb, float* __restrict__ gfb) {
    const int t = blockIdx.x * 256 + threadIdx.x;
    if (t < 2048) {
        const int i = t >> 10, cth = t & 1023;
        const int gate = (cth >> 4) & 3;
        const int dim = ((cth >> 6) << 4) | (cth & 15);
        const int orig = gate * 256 + dim;
        pb[t] = b_ih[i * 1024 + orig] + b_hh[i * 1024 + orig];
    } else if (t < 2304) gfb[t - 2048] = gm_b[t - 2048];
    else if (t < 2560) gfb[t - 2048] = fm_b[t - 2304];
}

__global__ __launch_bounds__(256)
void readout_reduce(const float* __restrict__ RO, float* __restrict__ out) {
    const int g = threadIdx.x;
    const int v0 = blockIdx.x * 128;
    float acc = 0.f;
    const int vend = (v0 + 128 < NND) ? v0 + 128 : NND;
    for (int v = v0; v < vend; ++v) {
        acc += sigf(RO[(size_t)v * 512 + g]) * RO[(size_t)v * 512 + 256 + g];
    }
    atomicAdd(&out[g], acc);
}

extern "C" void kernel_launch(void* const* d_in, const int* in_sizes, int n_in,
                              void* d_out, int out_size, void* d_ws, size_t ws_size,
                              hipStream_t stream) {
    const float* x         = (const float*)d_in[0];
    const float* edge_attr = (const float*)d_in[1];
    const int*   eidx      = (const int*)d_in[2];
    const float* fe1_W     = (const float*)d_in[3];
    const float* fe1_b     = (const float*)d_in[4];
    const float* fe2_W     = (const float*)d_in[5];
    const float* fe2_b     = (const float*)d_in[6];
    const float* W_ih      = (const float*)d_in[7];
    const float* W_hh      = (const float*)d_in[8];
    const float* b_ih      = (const float*)d_in[9];
    const float* b_hh      = (const float*)d_in[10];
    const float* gm_W      = (const float*)d_in[11];
    const float* gm_b      = (const float*)d_in[12];
    const float* fm_W      = (const float*)d_in[13];
    const float* fm_b      = (const float*)d_in[14];
    float* out = (float*)d_out;

    const int* src = eidx;
    const int* dst = eidx + NED;

    // ---- workspace layout (float offsets) ---------------------------------
    float* ws = (float*)d_ws;
    unsigned short* UVb  = (unsigned short*)ws;
    float*          s    = ws + 5120000L;
    float*          RO   = ws;
    unsigned short* sb   = (unsigned short*)(ws + 10240000L);
    float*          c    = ws + 12800000L;
    unsigned short* habA = (unsigned short*)(ws + 17920000L);
    unsigned short* wb   = (unsigned short*)(ws + 23040000L);
    float*          pb   = ws + 23860000L;
    float*          gfb  = ws + 23862048L;
    int*            ib   = (int*)(ws + 23870000L);
    int* deg    = ib;                 // 20000
    int* off    = ib + 20000;         // 20001
    int* cursor = ib + 40001;         // 20000
    int* perm   = ib + 60002;         // 320000
    int* srcS   = ib + 380002;        // 320000
    int* dstS   = ib + 700002;        // 320000 -> ends 1020002
    unsigned short* EABs = (unsigned short*)(ws + 24900000L);
    unsigned short* habB = (unsigned short*)(ws + 45380000L);

    // weight table offsets (bf16 elements)
    const long WUV = 0;        // [i]: 512x256  (+i*131072)
    const long WEB = 262144;   // [i]: 256x128  (+i*32768)
    const long WF2 = 327680;   // [i]: 256x256  (+i*65536)
    const long WG  = 458752;   // [i]: 1024x512 (+i*524288) gate-interleaved
    const long WGM = 1507328;  // 512x256

    // ---- setup -------------------------------------------------------------
    hipMemsetAsync(c, 0, (size_t)NND * DD * 4, stream);
    hipMemsetAsync(deg, 0, (size_t)NND * 4, stream);
    count_deg<<<(NED + 255) / 256, 256, 0, stream>>>(dst, deg);
    scan_offsets<<<1, 1024, 0, stream>>>(deg, off, cursor);
    scatter_edges<<<(NED + 255) / 256, 256, 0, stream>>>(dst, src, cursor, perm, srcS, dstS);
    prep_bias<<<10, 256, 0, stream>>>(b_ih, b_hh, gm_b, fm_b, pb, gfb);
    cast_blk<<<5000, 256, 0, stream>>>(x, 256, 0, NND, 256, habA, 512, 0, 0);
    gcvt<<<40000, 256, 0, stream>>>(edge_attr, perm, EABs);
    cast_weights<<<1600, 256, 0, stream>>>(fe1_W, fe2_W, W_ih, W_hh, gm_W, fm_W, wb);

    const dim3 gUV(157, 4), gF2(157, 2), gGT(157, 8), gRO(157, 4), gE(2500, 2);

    unsigned short* habC = habA;
    unsigned short* habN = habB;
    for (int i = 0; i < 2; ++i) {
        mgemm<1><<<gUV, 256, 0, stream>>>(habC, 512, wb + WUV + i * 131072,
                                          nullptr, UVb, NND, 512, 256, nullptr);
        hipMemsetAsync(s, 0, (size_t)NND * DD * 4, stream);
        edge_fused<<<gE, 256, 0, stream>>>(EABs, wb + WEB + i * 32768,
                                           fe1_b + (size_t)i * 256, UVb, srcS, dstS, s);
        cast_blk<<<5000, 256, 0, stream>>>(s, 256, 0, NND, 256, sb, 256, 0, 0);
        mgemm<2><<<gF2, 256, 0, stream>>>(sb, 256, wb + WF2 + i * 65536,
                                          fe2_b + (size_t)i * 256, habC, NND, 256, 256, deg);
        gemm_lstm<<<gGT, 256, 0, stream>>>(habC, wb + WG + i * 524288,
                                           pb + (size_t)i * 1024, c, habN, NND);
        unsigned short* tmp = habC; habC = habN; habN = tmp;
    }

    mgemm<0><<<gRO, 256, 0, stream>>>(habC, 512, wb + WGM, gfb, RO, NND, 512, 256, nullptr);
    hipMemsetAsync(out, 0, 256 * 4, stream);
    readout_reduce<<<157, 256, 0, stream>>>(RO, out);
}